// Round 5
// baseline (357.508 us; speedup 1.0000x reference)
//
#include <hip/hip_runtime.h>

#define N_NODES 50000
#define E_EDGES 800000
#define R_REL 3
#define NSEG (N_NODES * R_REL)    // 150000 (dst,rel) segments
#define DH 128
#define KDIM 512                  // A row: [mean_r0 | mean_r1 | mean_r2 | x/h] in bf16
#define ROWB 1024                 // bytes per A row
#define BATCHES 256
#define NCLASS 10
#define EPSV 1e-5f
#define SCAN1_BLOCKS ((NSEG + 1023) / 1024)   // 147

typedef __attribute__((ext_vector_type(8))) short short8v;
typedef __attribute__((ext_vector_type(4))) float float4v;
typedef unsigned short ushort_t;

__device__ __forceinline__ ushort_t f2bf(float f) {
    union { float f; unsigned u; } x; x.f = f;
    unsigned r = x.u + 0x7FFFu + ((x.u >> 16) & 1u);
    return (ushort_t)(r >> 16);
}
__device__ __forceinline__ float bf2f(ushort_t h) {
    union { unsigned u; float f; } x; x.u = ((unsigned)h) << 16;
    return x.f;
}
__device__ __forceinline__ float u2f(unsigned u) {
    union { unsigned u; float f; } x; x.u = u;
    return x.f;
}

// ---------------------------------------------------------------- build x (bf16) into A[n] x-slot
__global__ void build_x_kernel(const int* __restrict__ xi,
                               const float* __restrict__ se,
                               const float* __restrict__ ce,
                               const float* __restrict__ pe,
                               ushort_t* __restrict__ A) {
    int tid = blockIdx.x * blockDim.x + threadIdx.x;   // N*16 threads
    int node = tid >> 4, c = tid & 15;                 // c -> cols c*8..c*8+7
    if (node >= N_NODES) return;
    int i0 = xi[node * 3 + 0];
    int i1 = xi[node * 3 + 1];
    int i2 = xi[node * 3 + 2];
    i2 = i2 < 0 ? 0 : (i2 > 24 ? 24 : i2);
    const float4* sa = reinterpret_cast<const float4*>(se + (size_t)i0 * DH + c * 8);
    const float4* sb = reinterpret_cast<const float4*>(ce + (size_t)i1 * DH + c * 8);
    const float4* sp = reinterpret_cast<const float4*>(pe + (size_t)i2 * DH + c * 8);
    short8v o;
    #pragma unroll
    for (int q = 0; q < 2; ++q) {
        float4 a = sa[q], b = sb[q], p = sp[q];
        o[q * 4 + 0] = (short)f2bf(a.x + b.x + p.x);
        o[q * 4 + 1] = (short)f2bf(a.y + b.y + p.y);
        o[q * 4 + 2] = (short)f2bf(a.z + b.z + p.z);
        o[q * 4 + 3] = (short)f2bf(a.w + b.w + p.w);
    }
    *reinterpret_cast<short8v*>(A + (size_t)node * KDIM + 3 * DH + c * 8) = o;
}

// ---------------------------------------------------------------- per-(dst,rel) degree
__global__ void count_seg_kernel(const int* __restrict__ ei, const int* __restrict__ et,
                                 int* __restrict__ cnt3) {
    int e = blockIdx.x * blockDim.x + threadIdx.x;
    if (e >= E_EDGES) return;
    atomicAdd(&cnt3[ei[E_EDGES + e] * R_REL + et[e]], 1);
}

// ---------------------------------------------------------------- hierarchical exclusive scan (1024-thr L1)
__global__ void scan1_kernel(const int* __restrict__ cnt, int* __restrict__ offs,
                             int* __restrict__ aux) {
    __shared__ int sh[1024];
    int i = blockIdx.x * 1024 + threadIdx.x;
    int v = (i < NSEG) ? cnt[i] : 0;
    sh[threadIdx.x] = v;
    __syncthreads();
    for (int d = 1; d < 1024; d <<= 1) {
        int t = (threadIdx.x >= (unsigned)d) ? sh[threadIdx.x - d] : 0;
        __syncthreads();
        sh[threadIdx.x] += t;
        __syncthreads();
    }
    if (i < NSEG) offs[i] = sh[threadIdx.x] - v;      // exclusive
    if (threadIdx.x == 1023) aux[blockIdx.x] = sh[1023];
}

__global__ void scan2_kernel(int* __restrict__ aux) {
    __shared__ int sh[256];
    int t = threadIdx.x;
    int v = (t < SCAN1_BLOCKS) ? aux[t] : 0;
    sh[t] = v;
    __syncthreads();
    for (int d = 1; d < 256; d <<= 1) {
        int u = (t >= d) ? sh[t - d] : 0;
        __syncthreads();
        sh[t] += u;
        __syncthreads();
    }
    if (t < SCAN1_BLOCKS) aux[t] = sh[t] - v;         // exclusive
}

__global__ void scan3_kernel(int* __restrict__ offs, const int* __restrict__ aux) {
    int i = blockIdx.x * 1024 + threadIdx.x;
    if (i < NSEG) offs[i] += aux[blockIdx.x];
    if (i == 0) offs[NSEG] = E_EDGES;
}

// ---------------------------------------------------------------- fill (reverse, cnt3 as cursor)
// payload = byte offset of src's x-slot: src*ROWB + 768
__global__ void fill_kernel(const int* __restrict__ ei, const int* __restrict__ et,
                            const int* __restrict__ offs3, int* __restrict__ cnt3,
                            int* __restrict__ elist) {
    int e = blockIdx.x * blockDim.x + threadIdx.x;
    if (e >= E_EDGES) return;
    int src = ei[e];
    int seg = ei[E_EDGES + e] * R_REL + et[e];
    int pos = offs3[seg] + atomicSub(&cnt3[seg], 1) - 1;
    elist[pos] = src * ROWB + 3 * DH * 2;
}

// ---------------------------------------------------------------- batch segment bounds (batch is sorted)
__global__ void bounds_kernel(const int* __restrict__ batch, int* __restrict__ bstart) {
    int b = blockIdx.x * blockDim.x + threadIdx.x;
    if (b > BATCHES) return;
    int lo = 0, hi = N_NODES;
    while (lo < hi) {
        int mid = (lo + hi) >> 1;
        if (batch[mid] < b) lo = mid + 1; else hi = mid;
    }
    bstart[b] = lo;
}

// ---------------------------------------------------------------- weight pre-pack into MFMA B-frag order
__global__ void prepack_w_kernel(const float* __restrict__ W1, const float* __restrict__ root1,
                                 const float* __restrict__ W2, const float* __restrict__ root2,
                                 ushort_t* __restrict__ Wf1, ushort_t* __restrict__ Wf2) {
    int tid = blockIdx.x * blockDim.x + threadIdx.x;   // 2*16*8*64 = 16384
    if (tid >= 16384) return;
    int L = tid >> 13;
    int rem = tid & 8191;
    int ks = rem >> 9;
    int nt = (rem >> 6) & 7;
    int l = rem & 63;
    const float* W = L ? W2 : W1;
    const float* root = L ? root2 : root1;
    ushort_t* dst = (L ? Wf2 : Wf1) + (size_t)rem * 8;
    int col = nt * 16 + (l & 15);
    int kb = ks * 32 + (l >> 4) * 8;
    short8v o;
    #pragma unroll
    for (int j = 0; j < 8; ++j) {
        int k = kb + j;
        float w = (k < 384) ? W[(size_t)k * DH + col] : root[(size_t)(k - 384) * DH + col];
        o[j] = (short)f2bf(w);
    }
    *reinterpret_cast<short8v*>(dst) = o;
}

// ---------------------------------------------------------------- BN(eval) constant prep
__global__ void bn_prep_kernel(const float* __restrict__ b1, const float* __restrict__ g1,
                               const float* __restrict__ be1, const float* __restrict__ m1,
                               const float* __restrict__ v1,
                               const float* __restrict__ b2, const float* __restrict__ g2,
                               const float* __restrict__ be2, const float* __restrict__ m2,
                               const float* __restrict__ v2,
                               float* __restrict__ sc1, float* __restrict__ sh1,
                               float* __restrict__ sc2, float* __restrict__ sh2) {
    int t = threadIdx.x;
    if (t < DH) {
        float s = g1[t] * rsqrtf(v1[t] + EPSV);
        sc1[t] = s;
        sh1[t] = (b1[t] - m1[t]) * s + be1[t];
    } else if (t < 2 * DH) {
        int c = t - DH;
        float s = g2[c] * rsqrtf(v2[c] + EPSV);
        sc2[c] = s;
        sh2[c] = (b2[c] - m2[c]) * s + be2[c];
    }
}

// ---------------------------------------------------------------- gather aggregation: one wave per node
// lane l handles dword l (cols 2l, 2l+1); 3 (dst,rel) segments, branch-free, no divergence.
__global__ __launch_bounds__(256) void agg_kernel(const char* __restrict__ Ab,   // A as bytes
                                                  const int* __restrict__ offs3,
                                                  const int* __restrict__ elist,
                                                  char* __restrict__ Aob) {
    int wid = threadIdx.x >> 6, lane = threadIdx.x & 63;
    int n = blockIdx.x * 4 + wid;
    if (n >= N_NODES) return;
    int s0 = offs3[3 * n + 0];
    int s1 = offs3[3 * n + 1];
    int s2 = offs3[3 * n + 2];
    int s3 = offs3[3 * n + 3];
    int lb = lane * 4;

    float lo0 = 0, hi0 = 0, lo1 = 0, hi1 = 0, lo2 = 0, hi2 = 0;

    #define RUN_SEG(BEG, END, ALO, AHI)                                          \
    {                                                                            \
        int i = (BEG);                                                           \
        if (i < (END)) {                                                         \
            unsigned u = *reinterpret_cast<const unsigned*>(Ab + elist[i] + lb); \
            for (;;) {                                                           \
                int inx = i + 1;                                                 \
                unsigned un = 0;                                                 \
                if (inx < (END))                                                 \
                    un = *reinterpret_cast<const unsigned*>(Ab + elist[inx] + lb); \
                ALO += u2f(u << 16);                                             \
                AHI += u2f(u & 0xFFFF0000u);                                     \
                if (inx >= (END)) break;                                         \
                u = un; i = inx;                                                 \
            }                                                                    \
        }                                                                        \
    }

    RUN_SEG(s0, s1, lo0, hi0)
    RUN_SEG(s1, s2, lo1, hi1)
    RUN_SEG(s2, s3, lo2, hi2)
    #undef RUN_SEG

    int c0 = s1 - s0, c1 = s2 - s1, c2 = s3 - s2;
    float i0 = c0 ? 1.f / c0 : 0.f;
    float i1 = c1 ? 1.f / c1 : 0.f;
    float i2 = c2 ? 1.f / c2 : 0.f;
    char* base = Aob + (size_t)n * ROWB + lb;
    unsigned o;
    o = (unsigned)f2bf(lo0 * i0) | ((unsigned)f2bf(hi0 * i0) << 16);
    *reinterpret_cast<unsigned*>(base + 0 * 256) = o;
    o = (unsigned)f2bf(lo1 * i1) | ((unsigned)f2bf(hi1 * i1) << 16);
    *reinterpret_cast<unsigned*>(base + 1 * 256) = o;
    o = (unsigned)f2bf(lo2 * i2) | ((unsigned)f2bf(hi2 * i2) << 16);
    *reinterpret_cast<unsigned*>(base + 2 * 256) = o;
}

// ---------------------------------------------------------------- MFMA GEMM + BN + ReLU
__global__ __launch_bounds__(256) void gemm_mfma_kernel(const ushort_t* __restrict__ A,
                                                        const ushort_t* __restrict__ Wf,
                                                        const float* __restrict__ sc,
                                                        const float* __restrict__ sh,
                                                        ushort_t* __restrict__ Aout) {
    int w = threadIdx.x >> 6, l = threadIdx.x & 63;
    int base = blockIdx.x * 64 + w * 16;
    int arow = base + (l & 15);
    if (arow >= N_NODES) arow = N_NODES - 1;           // clamp loads; stores guarded
    const short8v* ap = reinterpret_cast<const short8v*>(A + (size_t)arow * KDIM + (l >> 4) * 8);
    const short8v* wf = reinterpret_cast<const short8v*>(Wf) + l;

    float4v acc[8];
    #pragma unroll
    for (int nt = 0; nt < 8; ++nt) acc[nt] = (float4v){0.f, 0.f, 0.f, 0.f};

    #pragma unroll 4
    for (int ks = 0; ks < 16; ++ks) {
        short8v a = ap[ks * 4];
        const short8v* bp = wf + ks * 512;
        #pragma unroll
        for (int nt = 0; nt < 8; ++nt) {
            short8v b = bp[nt * 64];
            acc[nt] = __builtin_amdgcn_mfma_f32_16x16x32_bf16(a, b, acc[nt], 0, 0, 0);
        }
    }

    int colb = l & 15;
    int rowq = (l >> 4) * 4;
    #pragma unroll
    for (int nt = 0; nt < 8; ++nt) {
        int col = nt * 16 + colb;
        float scv = sc[col], shv = sh[col];
        #pragma unroll
        for (int r = 0; r < 4; ++r) {
            int row = base + rowq + r;
            if (row < N_NODES) {
                float val = fmaxf(acc[nt][r] * scv + shv, 0.f);
                Aout[(size_t)row * KDIM + 3 * DH + col] = f2bf(val);
            }
        }
    }
}

// ---------------------------------------------------------------- fused global-mean-pool + classifier
__global__ __launch_bounds__(256) void pool_cls_kernel(
        const ushort_t* __restrict__ h,             // x/h slot rows, stride KDIM
        const int* __restrict__ bstart,
        const float* __restrict__ clsW,
        const float* __restrict__ clsb,
        float* __restrict__ out) {
    __shared__ float hsh[DH];
    int b = blockIdx.x;
    int t = threadIdx.x;
    int c = t & 127;
    int half = t >> 7;
    int beg = bstart[b], end = bstart[b + 1];
    float s = 0.f;
    for (int n = beg + half; n < end; n += 2)
        s += bf2f(h[(size_t)n * KDIM + c]);
    if (half == 1) hsh[c] = s;
    __syncthreads();
    if (half == 0) {
        float cnt = (float)(end - beg);
        float inv = cnt > 0.f ? 1.f / cnt : 1.f;
        hsh[c] = (s + hsh[c]) * inv;
    }
    __syncthreads();
    if (t < NCLASS) {
        float acc = clsb[t];
        #pragma unroll 16
        for (int d = 0; d < DH; ++d)
            acc += hsh[d] * clsW[d * NCLASS + t];
        out[b * NCLASS + t] = acc;
    }
}

// ---------------------------------------------------------------- launch
extern "C" void kernel_launch(void* const* d_in, const int* in_sizes, int n_in,
                              void* d_out, int out_size, void* d_ws, size_t ws_size,
                              hipStream_t stream) {
    const int*   x_idx  = (const int*)d_in[0];
    const int*   eidx   = (const int*)d_in[1];
    const int*   etype  = (const int*)d_in[2];
    const int*   batch  = (const int*)d_in[3];
    const float* se     = (const float*)d_in[4];
    const float* ce     = (const float*)d_in[5];
    const float* pe     = (const float*)d_in[6];
    const float* W1     = (const float*)d_in[7];
    const float* root1  = (const float*)d_in[8];
    const float* b1     = (const float*)d_in[9];
    const float* g1     = (const float*)d_in[10];
    const float* beta1  = (const float*)d_in[11];
    const float* m1     = (const float*)d_in[12];
    const float* v1     = (const float*)d_in[13];
    const float* W2     = (const float*)d_in[14];
    const float* root2  = (const float*)d_in[15];
    const float* b2     = (const float*)d_in[16];
    const float* g2     = (const float*)d_in[17];
    const float* beta2  = (const float*)d_in[18];
    const float* m2     = (const float*)d_in[19];
    const float* v2     = (const float*)d_in[20];
    const float* clsW   = (const float*)d_in[21];
    const float* clsb   = (const float*)d_in[22];
    float* out = (float*)d_out;

    // workspace layout (16B-aligned blocks)
    char* ws = (char*)d_ws;
    const size_t A_bytes     = (size_t)N_NODES * KDIM * 2;   // 51,200,000
    const size_t elist_bytes = (size_t)E_EDGES * 4;          //  3,200,000
    const size_t offs3_pad   = 600064;                       // (NSEG+1)*4 padded
    const size_t cnt3_pad    = 600064;
    ushort_t* A      = (ushort_t*)(ws);
    int*      elist  = (int*)(ws + A_bytes);
    int*      offs3  = (int*)(ws + A_bytes + elist_bytes);
    int*      cnt3   = (int*)(ws + A_bytes + elist_bytes + offs3_pad);
    char*     p      = ws + A_bytes + elist_bytes + offs3_pad + cnt3_pad;
    int*      aux    = (int*)p;            p += 1024;
    int*      bstart = (int*)p;            p += 1088;
    ushort_t* Wf1    = (ushort_t*)p;       p += 131072;
    ushort_t* Wf2    = (ushort_t*)p;       p += 131072;
    float*    sc1    = (float*)p;          p += 512;
    float*    sh1    = (float*)p;          p += 512;
    float*    sc2    = (float*)p;          p += 512;
    float*    sh2    = (float*)p;          p += 512;

    const int TB = 256;

    hipMemsetAsync(cnt3, 0, (size_t)NSEG * 4, stream);

    // x embeddings (bf16) -> A x-slot
    build_x_kernel<<<(N_NODES * 16 + TB - 1) / TB, TB, 0, stream>>>(x_idx, se, ce, pe, A);

    // (dst,rel)-segmented CSR + batch bounds + weight/BN prepack
    count_seg_kernel<<<(E_EDGES + TB - 1) / TB, TB, 0, stream>>>(eidx, etype, cnt3);
    scan1_kernel<<<SCAN1_BLOCKS, 1024, 0, stream>>>(cnt3, offs3, aux);
    scan2_kernel<<<1, 256, 0, stream>>>(aux);
    scan3_kernel<<<SCAN1_BLOCKS, 1024, 0, stream>>>(offs3, aux);
    fill_kernel<<<(E_EDGES + TB - 1) / TB, TB, 0, stream>>>(eidx, etype, offs3, cnt3, elist);
    bounds_kernel<<<2, 256, 0, stream>>>(batch, bstart);
    prepack_w_kernel<<<64, 256, 0, stream>>>(W1, root1, W2, root2, Wf1, Wf2);
    bn_prep_kernel<<<1, 256, 0, stream>>>(b1, g1, beta1, m1, v1,
                                          b2, g2, beta2, m2, v2,
                                          sc1, sh1, sc2, sh2);

    // ----- layer 1
    agg_kernel<<<(N_NODES + 3) / 4, 256, 0, stream>>>((const char*)A, offs3, elist, (char*)A);
    gemm_mfma_kernel<<<(N_NODES + 63) / 64, 256, 0, stream>>>(A, Wf1, sc1, sh1, A);

    // ----- layer 2
    agg_kernel<<<(N_NODES + 3) / 4, 256, 0, stream>>>((const char*)A, offs3, elist, (char*)A);
    gemm_mfma_kernel<<<(N_NODES + 63) / 64, 256, 0, stream>>>(A, Wf2, sc2, sh2, A);

    // ----- fused global mean pool + classifier
    pool_cls_kernel<<<BATCHES, 256, 0, stream>>>(A + 3 * DH, bstart, clsW, clsb, out);
}

// Round 6
// 280.879 us; speedup vs baseline: 1.2728x; 1.2728x over previous
//
#include <hip/hip_runtime.h>

#define N_NODES 50000
#define E_EDGES 800000
#define R_REL 3
#define NSEG (N_NODES * R_REL)    // 150000 (dst,rel) segments
#define DH 128
#define KDIM 512                  // A row: [mean_r0 | mean_r1 | mean_r2 | x/h] in bf16
#define ROWB 1024                 // bytes per A row
#define XOFF (3 * DH * 2)         // byte offset of x/h slot (768)
#define BATCHES 256
#define NCLASS 10
#define EPSV 1e-5f
#define SCAN1_BLOCKS ((NSEG + 1023) / 1024)   // 147

typedef __attribute__((ext_vector_type(8))) short short8v;
typedef __attribute__((ext_vector_type(4))) unsigned uint4v;
typedef __attribute__((ext_vector_type(4))) float float4v;
typedef unsigned short ushort_t;

__device__ __forceinline__ ushort_t f2bf(float f) {
    union { float f; unsigned u; } x; x.f = f;
    unsigned r = x.u + 0x7FFFu + ((x.u >> 16) & 1u);
    return (ushort_t)(r >> 16);
}
__device__ __forceinline__ float bf2f(ushort_t h) {
    union { unsigned u; float f; } x; x.u = ((unsigned)h) << 16;
    return x.f;
}
__device__ __forceinline__ float u2f(unsigned u) {
    union { unsigned u; float f; } x; x.u = u;
    return x.f;
}

// ---------------------------------------------------------------- build x (bf16) + per-(dst,rel) count, fused
__global__ void build_count_kernel(const int* __restrict__ xi,
                                   const float* __restrict__ se,
                                   const float* __restrict__ ce,
                                   const float* __restrict__ pe,
                                   ushort_t* __restrict__ A,
                                   const int* __restrict__ ei,
                                   const int* __restrict__ et,
                                   int* __restrict__ cnt3) {
    int tid = blockIdx.x * blockDim.x + threadIdx.x;
    if (tid < N_NODES * 16) {
        int node = tid >> 4, c = tid & 15;
        int i0 = xi[node * 3 + 0];
        int i1 = xi[node * 3 + 1];
        int i2 = xi[node * 3 + 2];
        i2 = i2 < 0 ? 0 : (i2 > 24 ? 24 : i2);
        const float4* sa = reinterpret_cast<const float4*>(se + (size_t)i0 * DH + c * 8);
        const float4* sb = reinterpret_cast<const float4*>(ce + (size_t)i1 * DH + c * 8);
        const float4* sp = reinterpret_cast<const float4*>(pe + (size_t)i2 * DH + c * 8);
        short8v o;
        #pragma unroll
        for (int q = 0; q < 2; ++q) {
            float4 a = sa[q], b = sb[q], p = sp[q];
            o[q * 4 + 0] = (short)f2bf(a.x + b.x + p.x);
            o[q * 4 + 1] = (short)f2bf(a.y + b.y + p.y);
            o[q * 4 + 2] = (short)f2bf(a.z + b.z + p.z);
            o[q * 4 + 3] = (short)f2bf(a.w + b.w + p.w);
        }
        *reinterpret_cast<short8v*>(A + (size_t)node * KDIM + 3 * DH + c * 8) = o;
    } else {
        int e = tid - N_NODES * 16;
        if (e < E_EDGES)
            atomicAdd(&cnt3[ei[E_EDGES + e] * R_REL + et[e]], 1);
    }
}

// ---------------------------------------------------------------- hierarchical exclusive scan
__global__ void scan1_kernel(const int* __restrict__ cnt, int* __restrict__ offs,
                             int* __restrict__ aux) {
    __shared__ int sh[1024];
    int i = blockIdx.x * 1024 + threadIdx.x;
    int v = (i < NSEG) ? cnt[i] : 0;
    sh[threadIdx.x] = v;
    __syncthreads();
    for (int d = 1; d < 1024; d <<= 1) {
        int t = (threadIdx.x >= (unsigned)d) ? sh[threadIdx.x - d] : 0;
        __syncthreads();
        sh[threadIdx.x] += t;
        __syncthreads();
    }
    if (i < NSEG) offs[i] = sh[threadIdx.x] - v;      // exclusive
    if (threadIdx.x == 1023) aux[blockIdx.x] = sh[1023];
}

__global__ void scan2_kernel(int* __restrict__ aux) {
    __shared__ int sh[256];
    int t = threadIdx.x;
    int v = (t < SCAN1_BLOCKS) ? aux[t] : 0;
    sh[t] = v;
    __syncthreads();
    for (int d = 1; d < 256; d <<= 1) {
        int u = (t >= d) ? sh[t - d] : 0;
        __syncthreads();
        sh[t] += u;
        __syncthreads();
    }
    if (t < SCAN1_BLOCKS) aux[t] = sh[t] - v;         // exclusive
}

__global__ void scan3_kernel(int* __restrict__ offs, const int* __restrict__ aux) {
    int i = blockIdx.x * 1024 + threadIdx.x;
    if (i < NSEG) offs[i] += aux[blockIdx.x];
    if (i == 0) offs[NSEG] = E_EDGES;
}

// ---------------------------------------------------------------- fill (reverse, cnt3 as cursor)
__global__ void fill_kernel(const int* __restrict__ ei, const int* __restrict__ et,
                            const int* __restrict__ offs3, int* __restrict__ cnt3,
                            int* __restrict__ elist) {
    int e = blockIdx.x * blockDim.x + threadIdx.x;
    if (e >= E_EDGES) return;
    int src = ei[e];
    int seg = ei[E_EDGES + e] * R_REL + et[e];
    int pos = offs3[seg] + atomicSub(&cnt3[seg], 1) - 1;
    elist[pos] = src * ROWB + XOFF;
}

// ---------------------------------------------------------------- setup: weight prepack + batch bounds + BN consts
__global__ void setup_kernel(const float* __restrict__ W1, const float* __restrict__ root1,
                             const float* __restrict__ W2, const float* __restrict__ root2,
                             ushort_t* __restrict__ Wf1, ushort_t* __restrict__ Wf2,
                             const int* __restrict__ batch, int* __restrict__ bstart,
                             const float* __restrict__ b1, const float* __restrict__ g1,
                             const float* __restrict__ be1, const float* __restrict__ m1,
                             const float* __restrict__ v1,
                             const float* __restrict__ b2, const float* __restrict__ g2,
                             const float* __restrict__ be2, const float* __restrict__ m2,
                             const float* __restrict__ v2,
                             float* __restrict__ sc1, float* __restrict__ sh1,
                             float* __restrict__ sc2, float* __restrict__ sh2) {
    int tid = blockIdx.x * blockDim.x + threadIdx.x;
    if (tid < 16384) {
        int L = tid >> 13;
        int rem = tid & 8191;
        int ks = rem >> 9;
        int nt = (rem >> 6) & 7;
        int l = rem & 63;
        const float* W = L ? W2 : W1;
        const float* root = L ? root2 : root1;
        ushort_t* dst = (L ? Wf2 : Wf1) + (size_t)rem * 8;
        int col = nt * 16 + (l & 15);
        int kb = ks * 32 + (l >> 4) * 8;
        short8v o;
        #pragma unroll
        for (int j = 0; j < 8; ++j) {
            int k = kb + j;
            float w = (k < 384) ? W[(size_t)k * DH + col] : root[(size_t)(k - 384) * DH + col];
            o[j] = (short)f2bf(w);
        }
        *reinterpret_cast<short8v*>(dst) = o;
    } else if (tid < 16384 + BATCHES + 1) {
        int b = tid - 16384;
        int lo = 0, hi = N_NODES;
        while (lo < hi) {
            int mid = (lo + hi) >> 1;
            if (batch[mid] < b) lo = mid + 1; else hi = mid;
        }
        bstart[b] = lo;
    } else if (tid < 16384 + 257 + DH) {
        int c = tid - 16384 - 257;
        float s = g1[c] * rsqrtf(v1[c] + EPSV);
        sc1[c] = s;
        sh1[c] = (b1[c] - m1[c]) * s + be1[c];
    } else if (tid < 16384 + 257 + 2 * DH) {
        int c = tid - 16384 - 257 - DH;
        float s = g2[c] * rsqrtf(v2[c] + EPSV);
        sc2[c] = s;
        sh2[c] = (b2[c] - m2[c]) * s + be2[c];
    }
}

// ---------------------------------------------------------------- gather aggregation: per-rel means
// 16 lanes per node (lane c -> bytes c*16..+16), 16 nodes per 256-thr block (4 streams/wave).
// Segmented CSR -> branch-free bodies; depth-2 software pipeline -> 2-3 loads in flight per stream.
__global__ __launch_bounds__(256) void agg_kernel(const char* __restrict__ Ab,
                                                  const int* __restrict__ offs3,
                                                  const int* __restrict__ elist,
                                                  char* __restrict__ Aob) {
    int t = threadIdx.x;
    int g = t >> 4, c = t & 15;
    int n = blockIdx.x * 16 + g;
    if (n >= N_NODES) return;
    int s0 = offs3[3 * n + 0];
    int s1 = offs3[3 * n + 1];
    int s2 = offs3[3 * n + 2];
    int s3 = offs3[3 * n + 3];
    int cb = c * 16;

    float r0l0 = 0, r0h0 = 0, r0l1 = 0, r0h1 = 0, r0l2 = 0, r0h2 = 0, r0l3 = 0, r0h3 = 0;
    float r1l0 = 0, r1h0 = 0, r1l1 = 0, r1h1 = 0, r1l2 = 0, r1h2 = 0, r1l3 = 0, r1h3 = 0;
    float r2l0 = 0, r2h0 = 0, r2l1 = 0, r2h1 = 0, r2l2 = 0, r2h2 = 0, r2l3 = 0, r2h3 = 0;

    #define RUN_SEG(BEG, END, L0, H0, L1, H1, L2, H2, L3, H3)                        \
    {                                                                                \
        int i = (BEG);                                                               \
        uint4v v0, v1;                                                               \
        if (i < (END))                                                               \
            v0 = *reinterpret_cast<const uint4v*>(Ab + elist[i] + cb);               \
        if (i + 1 < (END))                                                           \
            v1 = *reinterpret_cast<const uint4v*>(Ab + elist[i + 1] + cb);           \
        for (; i < (END); ++i) {                                                     \
            uint4v v2;                                                               \
            if (i + 2 < (END))                                                       \
                v2 = *reinterpret_cast<const uint4v*>(Ab + elist[i + 2] + cb);       \
            L0 += u2f(v0[0] << 16); H0 += u2f(v0[0] & 0xFFFF0000u);                  \
            L1 += u2f(v0[1] << 16); H1 += u2f(v0[1] & 0xFFFF0000u);                  \
            L2 += u2f(v0[2] << 16); H2 += u2f(v0[2] & 0xFFFF0000u);                  \
            L3 += u2f(v0[3] << 16); H3 += u2f(v0[3] & 0xFFFF0000u);                  \
            v0 = v1; v1 = v2;                                                        \
        }                                                                            \
    }

    RUN_SEG(s0, s1, r0l0, r0h0, r0l1, r0h1, r0l2, r0h2, r0l3, r0h3)
    RUN_SEG(s1, s2, r1l0, r1h0, r1l1, r1h1, r1l2, r1h2, r1l3, r1h3)
    RUN_SEG(s2, s3, r2l0, r2h0, r2l1, r2h1, r2l2, r2h2, r2l3, r2h3)
    #undef RUN_SEG

    int c0 = s1 - s0, c1 = s2 - s1, c2 = s3 - s2;
    float i0 = c0 ? 1.f / c0 : 0.f;
    float i1 = c1 ? 1.f / c1 : 0.f;
    float i2 = c2 ? 1.f / c2 : 0.f;
    char* base = Aob + (size_t)n * ROWB + cb;
    uint4v o;
    o[0] = (unsigned)f2bf(r0l0 * i0) | ((unsigned)f2bf(r0h0 * i0) << 16);
    o[1] = (unsigned)f2bf(r0l1 * i0) | ((unsigned)f2bf(r0h1 * i0) << 16);
    o[2] = (unsigned)f2bf(r0l2 * i0) | ((unsigned)f2bf(r0h2 * i0) << 16);
    o[3] = (unsigned)f2bf(r0l3 * i0) | ((unsigned)f2bf(r0h3 * i0) << 16);
    *reinterpret_cast<uint4v*>(base + 0 * 256) = o;
    o[0] = (unsigned)f2bf(r1l0 * i1) | ((unsigned)f2bf(r1h0 * i1) << 16);
    o[1] = (unsigned)f2bf(r1l1 * i1) | ((unsigned)f2bf(r1h1 * i1) << 16);
    o[2] = (unsigned)f2bf(r1l2 * i1) | ((unsigned)f2bf(r1h2 * i1) << 16);
    o[3] = (unsigned)f2bf(r1l3 * i1) | ((unsigned)f2bf(r1h3 * i1) << 16);
    *reinterpret_cast<uint4v*>(base + 1 * 256) = o;
    o[0] = (unsigned)f2bf(r2l0 * i2) | ((unsigned)f2bf(r2h0 * i2) << 16);
    o[1] = (unsigned)f2bf(r2l1 * i2) | ((unsigned)f2bf(r2h1 * i2) << 16);
    o[2] = (unsigned)f2bf(r2l2 * i2) | ((unsigned)f2bf(r2h2 * i2) << 16);
    o[3] = (unsigned)f2bf(r2l3 * i2) | ((unsigned)f2bf(r2h3 * i2) << 16);
    *reinterpret_cast<uint4v*>(base + 2 * 256) = o;
}

// ---------------------------------------------------------------- MFMA GEMM + BN + ReLU
__global__ __launch_bounds__(256) void gemm_mfma_kernel(const ushort_t* __restrict__ A,
                                                        const ushort_t* __restrict__ Wf,
                                                        const float* __restrict__ sc,
                                                        const float* __restrict__ sh,
                                                        ushort_t* __restrict__ Aout) {
    int w = threadIdx.x >> 6, l = threadIdx.x & 63;
    int base = blockIdx.x * 64 + w * 16;
    int arow = base + (l & 15);
    if (arow >= N_NODES) arow = N_NODES - 1;           // clamp loads; stores guarded
    const short8v* ap = reinterpret_cast<const short8v*>(A + (size_t)arow * KDIM + (l >> 4) * 8);
    const short8v* wf = reinterpret_cast<const short8v*>(Wf) + l;

    float4v acc[8];
    #pragma unroll
    for (int nt = 0; nt < 8; ++nt) acc[nt] = (float4v){0.f, 0.f, 0.f, 0.f};

    #pragma unroll 4
    for (int ks = 0; ks < 16; ++ks) {
        short8v a = ap[ks * 4];
        const short8v* bp = wf + ks * 512;
        #pragma unroll
        for (int nt = 0; nt < 8; ++nt) {
            short8v b = bp[nt * 64];
            acc[nt] = __builtin_amdgcn_mfma_f32_16x16x32_bf16(a, b, acc[nt], 0, 0, 0);
        }
    }

    int colb = l & 15;
    int rowq = (l >> 4) * 4;
    #pragma unroll
    for (int nt = 0; nt < 8; ++nt) {
        int col = nt * 16 + colb;
        float scv = sc[col], shv = sh[col];
        #pragma unroll
        for (int r = 0; r < 4; ++r) {
            int row = base + rowq + r;
            if (row < N_NODES) {
                float val = fmaxf(acc[nt][r] * scv + shv, 0.f);
                Aout[(size_t)row * KDIM + 3 * DH + col] = f2bf(val);
            }
        }
    }
}

// ---------------------------------------------------------------- fused global-mean-pool + classifier
__global__ __launch_bounds__(256) void pool_cls_kernel(
        const ushort_t* __restrict__ h,             // x/h slot rows, stride KDIM
        const int* __restrict__ bstart,
        const float* __restrict__ clsW,
        const float* __restrict__ clsb,
        float* __restrict__ out) {
    __shared__ float hsh[DH];
    int b = blockIdx.x;
    int t = threadIdx.x;
    int c = t & 127;
    int half = t >> 7;
    int beg = bstart[b], end = bstart[b + 1];
    float s = 0.f;
    for (int n = beg + half; n < end; n += 2)
        s += bf2f(h[(size_t)n * KDIM + c]);
    if (half == 1) hsh[c] = s;
    __syncthreads();
    if (half == 0) {
        float cnt = (float)(end - beg);
        float inv = cnt > 0.f ? 1.f / cnt : 1.f;
        hsh[c] = (s + hsh[c]) * inv;
    }
    __syncthreads();
    if (t < NCLASS) {
        float acc = clsb[t];
        #pragma unroll 16
        for (int d = 0; d < DH; ++d)
            acc += hsh[d] * clsW[d * NCLASS + t];
        out[b * NCLASS + t] = acc;
    }
}

// ---------------------------------------------------------------- launch
extern "C" void kernel_launch(void* const* d_in, const int* in_sizes, int n_in,
                              void* d_out, int out_size, void* d_ws, size_t ws_size,
                              hipStream_t stream) {
    const int*   x_idx  = (const int*)d_in[0];
    const int*   eidx   = (const int*)d_in[1];
    const int*   etype  = (const int*)d_in[2];
    const int*   batch  = (const int*)d_in[3];
    const float* se     = (const float*)d_in[4];
    const float* ce     = (const float*)d_in[5];
    const float* pe     = (const float*)d_in[6];
    const float* W1     = (const float*)d_in[7];
    const float* root1  = (const float*)d_in[8];
    const float* b1     = (const float*)d_in[9];
    const float* g1     = (const float*)d_in[10];
    const float* beta1  = (const float*)d_in[11];
    const float* m1     = (const float*)d_in[12];
    const float* v1     = (const float*)d_in[13];
    const float* W2     = (const float*)d_in[14];
    const float* root2  = (const float*)d_in[15];
    const float* b2     = (const float*)d_in[16];
    const float* g2     = (const float*)d_in[17];
    const float* beta2  = (const float*)d_in[18];
    const float* m2     = (const float*)d_in[19];
    const float* v2     = (const float*)d_in[20];
    const float* clsW   = (const float*)d_in[21];
    const float* clsb   = (const float*)d_in[22];
    float* out = (float*)d_out;

    // workspace layout (16B-aligned blocks)
    char* ws = (char*)d_ws;
    const size_t A_bytes     = (size_t)N_NODES * KDIM * 2;   // 51,200,000
    const size_t elist_bytes = (size_t)E_EDGES * 4;          //  3,200,000
    const size_t offs3_pad   = 600064;                       // (NSEG+1)*4 padded
    const size_t cnt3_pad    = 600064;
    ushort_t* A      = (ushort_t*)(ws);
    int*      elist  = (int*)(ws + A_bytes);
    int*      offs3  = (int*)(ws + A_bytes + elist_bytes);
    int*      cnt3   = (int*)(ws + A_bytes + elist_bytes + offs3_pad);
    char*     p      = ws + A_bytes + elist_bytes + offs3_pad + cnt3_pad;
    int*      aux    = (int*)p;            p += 1024;
    int*      bstart = (int*)p;            p += 1088;
    ushort_t* Wf1    = (ushort_t*)p;       p += 131072;
    ushort_t* Wf2    = (ushort_t*)p;       p += 131072;
    float*    sc1    = (float*)p;          p += 512;
    float*    sh1    = (float*)p;          p += 512;
    float*    sc2    = (float*)p;          p += 512;
    float*    sh2    = (float*)p;          p += 512;

    const int TB = 256;

    hipMemsetAsync(cnt3, 0, (size_t)NSEG * 4, stream);

    // fused: x embeddings (bf16) + (dst,rel) degree count
    build_count_kernel<<<(N_NODES * 16 + E_EDGES + TB - 1) / TB, TB, 0, stream>>>(
        x_idx, se, ce, pe, A, eidx, etype, cnt3);

    // fused setup: weight prepack + batch bounds + BN consts (independent of CSR)
    setup_kernel<<<67, 256, 0, stream>>>(W1, root1, W2, root2, Wf1, Wf2,
                                         batch, bstart,
                                         b1, g1, beta1, m1, v1,
                                         b2, g2, beta2, m2, v2,
                                         sc1, sh1, sc2, sh2);

    // (dst,rel)-segmented CSR
    scan1_kernel<<<SCAN1_BLOCKS, 1024, 0, stream>>>(cnt3, offs3, aux);
    scan2_kernel<<<1, 256, 0, stream>>>(aux);
    scan3_kernel<<<SCAN1_BLOCKS, 1024, 0, stream>>>(offs3, aux);
    fill_kernel<<<(E_EDGES + TB - 1) / TB, TB, 0, stream>>>(eidx, etype, offs3, cnt3, elist);

    // ----- layer 1
    agg_kernel<<<(N_NODES + 15) / 16, 256, 0, stream>>>((const char*)A, offs3, elist, (char*)A);
    gemm_mfma_kernel<<<(N_NODES + 63) / 64, 256, 0, stream>>>(A, Wf1, sc1, sh1, A);

    // ----- layer 2
    agg_kernel<<<(N_NODES + 15) / 16, 256, 0, stream>>>((const char*)A, offs3, elist, (char*)A);
    gemm_mfma_kernel<<<(N_NODES + 63) / 64, 256, 0, stream>>>(A, Wf2, sc2, sh2, A);

    // ----- fused global mean pool + classifier
    pool_cls_kernel<<<BATCHES, 256, 0, stream>>>(A + 3 * DH, bstart, clsW, clsb, out);
}

// Round 7
// 268.065 us; speedup vs baseline: 1.3337x; 1.0478x over previous
//
#include <hip/hip_runtime.h>

#define N_NODES 50000
#define E_EDGES 800000
#define R_REL 3
#define NSEG (N_NODES * R_REL)    // 150000 (dst,rel) segments
#define DH 128
#define KDIM 512                  // A row: [mean_r0 | mean_r1 | mean_r2 | x/h] in bf16
#define ROWB 1024                 // bytes per A row
#define XOFF (3 * DH * 2)         // byte offset of x/h slot (768)
#define BATCHES 256
#define NCLASS 10
#define EPSV 1e-5f

#define BSHIFT 7
#define BNODES 128                // nodes per bucket
#define NBUCK ((N_NODES + BNODES - 1) / BNODES)   // 391
#define SEGB (BNODES * R_REL)     // 384 segments per bucket
#define CAP 4096                  // LDS staging capacity (mean 2048, sigma ~45)

typedef __attribute__((ext_vector_type(8))) short short8v;
typedef __attribute__((ext_vector_type(4))) unsigned uint4v;
typedef __attribute__((ext_vector_type(4))) float float4v;
typedef unsigned short ushort_t;

__device__ __forceinline__ ushort_t f2bf(float f) {
    union { float f; unsigned u; } x; x.f = f;
    unsigned r = x.u + 0x7FFFu + ((x.u >> 16) & 1u);
    return (ushort_t)(r >> 16);
}
__device__ __forceinline__ float bf2f(ushort_t h) {
    union { unsigned u; float f; } x; x.u = ((unsigned)h) << 16;
    return x.f;
}
__device__ __forceinline__ float u2f(unsigned u) {
    union { unsigned u; float f; } x; x.u = u;
    return x.f;
}

// ---------------------------------------------------------------- build x (bf16) into A x-slot
__global__ void build_x_kernel(const int* __restrict__ xi,
                               const float* __restrict__ se,
                               const float* __restrict__ ce,
                               const float* __restrict__ pe,
                               ushort_t* __restrict__ A) {
    int tid = blockIdx.x * blockDim.x + threadIdx.x;   // N*16 threads
    int node = tid >> 4, c = tid & 15;
    if (node >= N_NODES) return;
    int i0 = xi[node * 3 + 0];
    int i1 = xi[node * 3 + 1];
    int i2 = xi[node * 3 + 2];
    i2 = i2 < 0 ? 0 : (i2 > 24 ? 24 : i2);
    const float4* sa = reinterpret_cast<const float4*>(se + (size_t)i0 * DH + c * 8);
    const float4* sb = reinterpret_cast<const float4*>(ce + (size_t)i1 * DH + c * 8);
    const float4* sp = reinterpret_cast<const float4*>(pe + (size_t)i2 * DH + c * 8);
    short8v o;
    #pragma unroll
    for (int q = 0; q < 2; ++q) {
        float4 a = sa[q], b = sb[q], p = sp[q];
        o[q * 4 + 0] = (short)f2bf(a.x + b.x + p.x);
        o[q * 4 + 1] = (short)f2bf(a.y + b.y + p.y);
        o[q * 4 + 2] = (short)f2bf(a.z + b.z + p.z);
        o[q * 4 + 3] = (short)f2bf(a.w + b.w + p.w);
    }
    *reinterpret_cast<short8v*>(A + (size_t)node * KDIM + 3 * DH + c * 8) = o;
}

// ---------------------------------------------------------------- bucket histogram (LDS-aggregated)
__global__ __launch_bounds__(256) void hist_kernel(const int* __restrict__ ei,
                                                   int* __restrict__ bcount) {
    __shared__ int lh[NBUCK];
    for (int i = threadIdx.x; i < NBUCK; i += 256) lh[i] = 0;
    __syncthreads();
    int stride = gridDim.x * 256;
    for (int e = blockIdx.x * 256 + threadIdx.x; e < E_EDGES; e += stride)
        atomicAdd(&lh[ei[E_EDGES + e] >> BSHIFT], 1);
    __syncthreads();
    for (int i = threadIdx.x; i < NBUCK; i += 256)
        if (lh[i]) atomicAdd(&bcount[i], lh[i]);
}

// ---------------------------------------------------------------- bucket scan (one 512-thr block)
__global__ __launch_bounds__(512) void bucket_scan_kernel(const int* __restrict__ bcount,
                                                          int* __restrict__ bbase,
                                                          int* __restrict__ bcur,
                                                          int* __restrict__ offs3) {
    __shared__ int sh[512];
    int t = threadIdx.x;
    int v = (t < NBUCK) ? bcount[t] : 0;
    sh[t] = v;
    __syncthreads();
    for (int d = 1; d < 512; d <<= 1) {
        int u = (t >= d) ? sh[t - d] : 0;
        __syncthreads();
        sh[t] += u;
        __syncthreads();
    }
    int excl = sh[t] - v;
    if (t < NBUCK) { bbase[t] = excl; bcur[t * 16] = excl; }   // cursors padded to 64B
    if (t == NBUCK - 1) bbase[NBUCK] = sh[t];                  // = E_EDGES
    if (t == 0) offs3[NSEG] = E_EDGES;
}

// ---------------------------------------------------------------- append edges to buckets
// concurrent appends -> adjacent positions -> line-coalesced writes
__global__ void append_kernel(const int* __restrict__ ei, const int* __restrict__ et,
                              int* __restrict__ bcur, int* __restrict__ tlist) {
    int e = blockIdx.x * blockDim.x + threadIdx.x;
    if (e >= E_EDGES) return;
    int src = ei[e];
    int dst = ei[E_EDGES + e];
    int r = et[e];
    int b = dst >> BSHIFT;
    int ls = (dst & (BNODES - 1)) * R_REL + r;                 // < 384
    int pos = atomicAdd(&bcur[b * 16], 1);
    tlist[pos] = (ls << 16) | src;                             // src < 2^16
}

// ---------------------------------------------------------------- per-bucket local sort (LDS)
// writes offs3 slice + elist slice, both coalesced
__global__ __launch_bounds__(512) void localsort_kernel(const int* __restrict__ tlist,
                                                        const int* __restrict__ bbase,
                                                        int* __restrict__ offs3,
                                                        int* __restrict__ elist) {
    __shared__ int hist[512];
    __shared__ int tl[CAP];
    __shared__ int el[CAP];
    int b = blockIdx.x, t = threadIdx.x;
    int ebeg = bbase[b], eend = bbase[b + 1];
    int cnt = eend - ebeg;
    int segbase = b * SEGB;
    hist[t] = 0;
    __syncthreads();

    if (cnt <= CAP) {
        for (int i = t; i < cnt; i += 512) {
            int pk = tlist[ebeg + i];
            tl[i] = pk;
            atomicAdd(&hist[pk >> 16], 1);
        }
        __syncthreads();
        int v = hist[t];
        for (int d = 1; d < 512; d <<= 1) {
            int u = (t >= d) ? hist[t - d] : 0;
            __syncthreads();
            hist[t] += u;
            __syncthreads();
        }
        int excl = hist[t] - v;
        if (t < SEGB && segbase + t < NSEG) offs3[segbase + t] = ebeg + excl;
        __syncthreads();
        hist[t] = excl;                                        // local cursor
        __syncthreads();
        for (int i = t; i < cnt; i += 512) {
            int pk = tl[i];
            int pos = atomicAdd(&hist[pk >> 16], 1);
            el[pos] = (pk & 0xFFFF) * ROWB + XOFF;
        }
        __syncthreads();
        for (int i = t; i < cnt; i += 512)
            elist[ebeg + i] = el[i];
    } else {
        // overflow fallback: two-pass via global memory (statistically unreachable)
        for (int i = t; i < cnt; i += 512)
            atomicAdd(&hist[tlist[ebeg + i] >> 16], 1);
        __syncthreads();
        int v = hist[t];
        for (int d = 1; d < 512; d <<= 1) {
            int u = (t >= d) ? hist[t - d] : 0;
            __syncthreads();
            hist[t] += u;
            __syncthreads();
        }
        int excl = hist[t] - v;
        if (t < SEGB && segbase + t < NSEG) offs3[segbase + t] = ebeg + excl;
        __syncthreads();
        hist[t] = excl;
        __syncthreads();
        for (int i = t; i < cnt; i += 512) {
            int pk = tlist[ebeg + i];
            int pos = atomicAdd(&hist[pk >> 16], 1);
            elist[ebeg + pos] = (pk & 0xFFFF) * ROWB + XOFF;
        }
    }
}

// ---------------------------------------------------------------- setup: weight prepack + batch bounds + BN consts
__global__ void setup_kernel(const float* __restrict__ W1, const float* __restrict__ root1,
                             const float* __restrict__ W2, const float* __restrict__ root2,
                             ushort_t* __restrict__ Wf1, ushort_t* __restrict__ Wf2,
                             const int* __restrict__ batch, int* __restrict__ bstart,
                             const float* __restrict__ b1, const float* __restrict__ g1,
                             const float* __restrict__ be1, const float* __restrict__ m1,
                             const float* __restrict__ v1,
                             const float* __restrict__ b2, const float* __restrict__ g2,
                             const float* __restrict__ be2, const float* __restrict__ m2,
                             const float* __restrict__ v2,
                             float* __restrict__ sc1, float* __restrict__ sh1,
                             float* __restrict__ sc2, float* __restrict__ sh2) {
    int tid = blockIdx.x * blockDim.x + threadIdx.x;
    if (tid < 16384) {
        int L = tid >> 13;
        int rem = tid & 8191;
        int l = rem & 63;
        int nt = (rem >> 6) & 7;
        int ks = rem >> 9;
        const float* W = L ? W2 : W1;
        const float* root = L ? root2 : root1;
        ushort_t* dst = (L ? Wf2 : Wf1) + (size_t)rem * 8;
        int col = nt * 16 + (l & 15);
        int kb = ks * 32 + (l >> 4) * 8;
        short8v o;
        #pragma unroll
        for (int j = 0; j < 8; ++j) {
            int k = kb + j;
            float w = (k < 384) ? W[(size_t)k * DH + col] : root[(size_t)(k - 384) * DH + col];
            o[j] = (short)f2bf(w);
        }
        *reinterpret_cast<short8v*>(dst) = o;
    } else if (tid < 16384 + BATCHES + 1) {
        int b = tid - 16384;
        int lo = 0, hi = N_NODES;
        while (lo < hi) {
            int mid = (lo + hi) >> 1;
            if (batch[mid] < b) lo = mid + 1; else hi = mid;
        }
        bstart[b] = lo;
    } else if (tid < 16384 + 257 + DH) {
        int c = tid - 16384 - 257;
        float s = g1[c] * rsqrtf(v1[c] + EPSV);
        sc1[c] = s;
        sh1[c] = (b1[c] - m1[c]) * s + be1[c];
    } else if (tid < 16384 + 257 + 2 * DH) {
        int c = tid - 16384 - 257 - DH;
        float s = g2[c] * rsqrtf(v2[c] + EPSV);
        sc2[c] = s;
        sh2[c] = (b2[c] - m2[c]) * s + be2[c];
    }
}

// ---------------------------------------------------------------- gather aggregation: per-rel means
// 16 lanes per node, 16 nodes per 256-thr block (4 streams/wave), depth-2 pipeline.
__global__ __launch_bounds__(256) void agg_kernel(const char* __restrict__ Ab,
                                                  const int* __restrict__ offs3,
                                                  const int* __restrict__ elist,
                                                  char* __restrict__ Aob) {
    int t = threadIdx.x;
    int g = t >> 4, c = t & 15;
    int n = blockIdx.x * 16 + g;
    if (n >= N_NODES) return;
    int s0 = offs3[3 * n + 0];
    int s1 = offs3[3 * n + 1];
    int s2 = offs3[3 * n + 2];
    int s3 = offs3[3 * n + 3];
    int cb = c * 16;

    float r0l0 = 0, r0h0 = 0, r0l1 = 0, r0h1 = 0, r0l2 = 0, r0h2 = 0, r0l3 = 0, r0h3 = 0;
    float r1l0 = 0, r1h0 = 0, r1l1 = 0, r1h1 = 0, r1l2 = 0, r1h2 = 0, r1l3 = 0, r1h3 = 0;
    float r2l0 = 0, r2h0 = 0, r2l1 = 0, r2h1 = 0, r2l2 = 0, r2h2 = 0, r2l3 = 0, r2h3 = 0;

    #define RUN_SEG(BEG, END, L0, H0, L1, H1, L2, H2, L3, H3)                        \
    {                                                                                \
        int i = (BEG);                                                               \
        uint4v v0, v1;                                                               \
        if (i < (END))                                                               \
            v0 = *reinterpret_cast<const uint4v*>(Ab + elist[i] + cb);               \
        if (i + 1 < (END))                                                           \
            v1 = *reinterpret_cast<const uint4v*>(Ab + elist[i + 1] + cb);           \
        for (; i < (END); ++i) {                                                     \
            uint4v v2;                                                               \
            if (i + 2 < (END))                                                       \
                v2 = *reinterpret_cast<const uint4v*>(Ab + elist[i + 2] + cb);       \
            L0 += u2f(v0[0] << 16); H0 += u2f(v0[0] & 0xFFFF0000u);                  \
            L1 += u2f(v0[1] << 16); H1 += u2f(v0[1] & 0xFFFF0000u);                  \
            L2 += u2f(v0[2] << 16); H2 += u2f(v0[2] & 0xFFFF0000u);                  \
            L3 += u2f(v0[3] << 16); H3 += u2f(v0[3] & 0xFFFF0000u);                  \
            v0 = v1; v1 = v2;                                                        \
        }                                                                            \
    }

    RUN_SEG(s0, s1, r0l0, r0h0, r0l1, r0h1, r0l2, r0h2, r0l3, r0h3)
    RUN_SEG(s1, s2, r1l0, r1h0, r1l1, r1h1, r1l2, r1h2, r1l3, r1h3)
    RUN_SEG(s2, s3, r2l0, r2h0, r2l1, r2h1, r2l2, r2h2, r2l3, r2h3)
    #undef RUN_SEG

    int c0 = s1 - s0, c1 = s2 - s1, c2 = s3 - s2;
    float i0 = c0 ? 1.f / c0 : 0.f;
    float i1 = c1 ? 1.f / c1 : 0.f;
    float i2 = c2 ? 1.f / c2 : 0.f;
    char* base = Aob + (size_t)n * ROWB + cb;
    uint4v o;
    o[0] = (unsigned)f2bf(r0l0 * i0) | ((unsigned)f2bf(r0h0 * i0) << 16);
    o[1] = (unsigned)f2bf(r0l1 * i0) | ((unsigned)f2bf(r0h1 * i0) << 16);
    o[2] = (unsigned)f2bf(r0l2 * i0) | ((unsigned)f2bf(r0h2 * i0) << 16);
    o[3] = (unsigned)f2bf(r0l3 * i0) | ((unsigned)f2bf(r0h3 * i0) << 16);
    *reinterpret_cast<uint4v*>(base + 0 * 256) = o;
    o[0] = (unsigned)f2bf(r1l0 * i1) | ((unsigned)f2bf(r1h0 * i1) << 16);
    o[1] = (unsigned)f2bf(r1l1 * i1) | ((unsigned)f2bf(r1h1 * i1) << 16);
    o[2] = (unsigned)f2bf(r1l2 * i1) | ((unsigned)f2bf(r1h2 * i1) << 16);
    o[3] = (unsigned)f2bf(r1l3 * i1) | ((unsigned)f2bf(r1h3 * i1) << 16);
    *reinterpret_cast<uint4v*>(base + 1 * 256) = o;
    o[0] = (unsigned)f2bf(r2l0 * i2) | ((unsigned)f2bf(r2h0 * i2) << 16);
    o[1] = (unsigned)f2bf(r2l1 * i2) | ((unsigned)f2bf(r2h1 * i2) << 16);
    o[2] = (unsigned)f2bf(r2l2 * i2) | ((unsigned)f2bf(r2h2 * i2) << 16);
    o[3] = (unsigned)f2bf(r2l3 * i2) | ((unsigned)f2bf(r2h3 * i2) << 16);
    *reinterpret_cast<uint4v*>(base + 2 * 256) = o;
}

// ---------------------------------------------------------------- MFMA GEMM + BN + ReLU
__global__ __launch_bounds__(256) void gemm_mfma_kernel(const ushort_t* __restrict__ A,
                                                        const ushort_t* __restrict__ Wf,
                                                        const float* __restrict__ sc,
                                                        const float* __restrict__ sh,
                                                        ushort_t* __restrict__ Aout) {
    int w = threadIdx.x >> 6, l = threadIdx.x & 63;
    int base = blockIdx.x * 64 + w * 16;
    int arow = base + (l & 15);
    if (arow >= N_NODES) arow = N_NODES - 1;           // clamp loads; stores guarded
    const short8v* ap = reinterpret_cast<const short8v*>(A + (size_t)arow * KDIM + (l >> 4) * 8);
    const short8v* wf = reinterpret_cast<const short8v*>(Wf) + l;

    float4v acc[8];
    #pragma unroll
    for (int nt = 0; nt < 8; ++nt) acc[nt] = (float4v){0.f, 0.f, 0.f, 0.f};

    #pragma unroll 4
    for (int ks = 0; ks < 16; ++ks) {
        short8v a = ap[ks * 4];
        const short8v* bp = wf + ks * 512;
        #pragma unroll
        for (int nt = 0; nt < 8; ++nt) {
            short8v b = bp[nt * 64];
            acc[nt] = __builtin_amdgcn_mfma_f32_16x16x32_bf16(a, b, acc[nt], 0, 0, 0);
        }
    }

    int colb = l & 15;
    int rowq = (l >> 4) * 4;
    #pragma unroll
    for (int nt = 0; nt < 8; ++nt) {
        int col = nt * 16 + colb;
        float scv = sc[col], shv = sh[col];
        #pragma unroll
        for (int r = 0; r < 4; ++r) {
            int row = base + rowq + r;
            if (row < N_NODES) {
                float val = fmaxf(acc[nt][r] * scv + shv, 0.f);
                Aout[(size_t)row * KDIM + 3 * DH + col] = f2bf(val);
            }
        }
    }
}

// ---------------------------------------------------------------- fused global-mean-pool + classifier
__global__ __launch_bounds__(256) void pool_cls_kernel(
        const ushort_t* __restrict__ h,             // x/h slot rows, stride KDIM
        const int* __restrict__ bstart,
        const float* __restrict__ clsW,
        const float* __restrict__ clsb,
        float* __restrict__ out) {
    __shared__ float hsh[DH];
    int b = blockIdx.x;
    int t = threadIdx.x;
    int c = t & 127;
    int half = t >> 7;
    int beg = bstart[b], end = bstart[b + 1];
    float s = 0.f;
    for (int n = beg + half; n < end; n += 2)
        s += bf2f(h[(size_t)n * KDIM + c]);
    if (half == 1) hsh[c] = s;
    __syncthreads();
    if (half == 0) {
        float cnt = (float)(end - beg);
        float inv = cnt > 0.f ? 1.f / cnt : 1.f;
        hsh[c] = (s + hsh[c]) * inv;
    }
    __syncthreads();
    if (t < NCLASS) {
        float acc = clsb[t];
        #pragma unroll 16
        for (int d = 0; d < DH; ++d)
            acc += hsh[d] * clsW[d * NCLASS + t];
        out[b * NCLASS + t] = acc;
    }
}

// ---------------------------------------------------------------- launch
extern "C" void kernel_launch(void* const* d_in, const int* in_sizes, int n_in,
                              void* d_out, int out_size, void* d_ws, size_t ws_size,
                              hipStream_t stream) {
    const int*   x_idx  = (const int*)d_in[0];
    const int*   eidx   = (const int*)d_in[1];
    const int*   etype  = (const int*)d_in[2];
    const int*   batch  = (const int*)d_in[3];
    const float* se     = (const float*)d_in[4];
    const float* ce     = (const float*)d_in[5];
    const float* pe     = (const float*)d_in[6];
    const float* W1     = (const float*)d_in[7];
    const float* root1  = (const float*)d_in[8];
    const float* b1     = (const float*)d_in[9];
    const float* g1     = (const float*)d_in[10];
    const float* beta1  = (const float*)d_in[11];
    const float* m1     = (const float*)d_in[12];
    const float* v1     = (const float*)d_in[13];
    const float* W2     = (const float*)d_in[14];
    const float* root2  = (const float*)d_in[15];
    const float* b2     = (const float*)d_in[16];
    const float* g2     = (const float*)d_in[17];
    const float* beta2  = (const float*)d_in[18];
    const float* m2     = (const float*)d_in[19];
    const float* v2     = (const float*)d_in[20];
    const float* clsW   = (const float*)d_in[21];
    const float* clsb   = (const float*)d_in[22];
    float* out = (float*)d_out;

    // workspace layout (16B-aligned blocks)
    char* ws = (char*)d_ws;
    const size_t A_bytes     = (size_t)N_NODES * KDIM * 2;   // 51,200,000
    const size_t elist_bytes = (size_t)E_EDGES * 4;          //  3,200,000
    const size_t tlist_bytes = (size_t)E_EDGES * 4;          //  3,200,000
    const size_t offs3_pad   = 600064;                       // (NSEG+1)*4 padded
    ushort_t* A      = (ushort_t*)(ws);
    int*      elist  = (int*)(ws + A_bytes);
    int*      tlist  = (int*)(ws + A_bytes + elist_bytes);
    int*      offs3  = (int*)(ws + A_bytes + elist_bytes + tlist_bytes);
    char*     p      = ws + A_bytes + elist_bytes + tlist_bytes + offs3_pad;
    int*      bcount = (int*)p;            p += 1600;        // 392 ints padded
    int*      bbase  = (int*)p;            p += 1600;        // 392 ints padded
    int*      bcur   = (int*)p;            p += NBUCK * 64;  // 64B-padded cursors
    int*      bstart = (int*)p;            p += 1088;
    ushort_t* Wf1    = (ushort_t*)p;       p += 131072;
    ushort_t* Wf2    = (ushort_t*)p;       p += 131072;
    float*    sc1    = (float*)p;          p += 512;
    float*    sh1    = (float*)p;          p += 512;
    float*    sc2    = (float*)p;          p += 512;
    float*    sh2    = (float*)p;          p += 512;

    const int TB = 256;

    hipMemsetAsync(bcount, 0, NBUCK * 4, stream);

    // x embeddings (bf16) -> A x-slot
    build_x_kernel<<<(N_NODES * 16 + TB - 1) / TB, TB, 0, stream>>>(x_idx, se, ce, pe, A);

    // fused setup: weight prepack + batch bounds + BN consts
    setup_kernel<<<67, 256, 0, stream>>>(W1, root1, W2, root2, Wf1, Wf2,
                                         batch, bstart,
                                         b1, g1, beta1, m1, v1,
                                         b2, g2, beta2, m2, v2,
                                         sc1, sh1, sc2, sh2);

    // bucketed (dst,rel) CSR build
    hist_kernel<<<64, 256, 0, stream>>>(eidx, bcount);
    bucket_scan_kernel<<<1, 512, 0, stream>>>(bcount, bbase, bcur, offs3);
    append_kernel<<<(E_EDGES + TB - 1) / TB, TB, 0, stream>>>(eidx, etype, bcur, tlist);
    localsort_kernel<<<NBUCK, 512, 0, stream>>>(tlist, bbase, offs3, elist);

    // ----- layer 1
    agg_kernel<<<(N_NODES + 15) / 16, 256, 0, stream>>>((const char*)A, offs3, elist, (char*)A);
    gemm_mfma_kernel<<<(N_NODES + 63) / 64, 256, 0, stream>>>(A, Wf1, sc1, sh1, A);

    // ----- layer 2
    agg_kernel<<<(N_NODES + 15) / 16, 256, 0, stream>>>((const char*)A, offs3, elist, (char*)A);
    gemm_mfma_kernel<<<(N_NODES + 63) / 64, 256, 0, stream>>>(A, Wf2, sc2, sh2, A);

    // ----- fused global mean pool + classifier
    pool_cls_kernel<<<BATCHES, 256, 0, stream>>>(A + 3 * DH, bstart, clsW, clsb, out);
}

// Round 8
// 235.192 us; speedup vs baseline: 1.5201x; 1.1398x over previous
//
#include <hip/hip_runtime.h>

#define N_NODES 50000
#define E_EDGES 800000
#define R_REL 3
#define NSEG (N_NODES * R_REL)    // 150000 (dst,rel) segments
#define DH 128
#define KDIM 512                  // A row: [mean_r0 | mean_r1 | mean_r2 | x/h] in bf16
#define ROWB 1024                 // bytes per A row
#define XOFF (3 * DH * 2)         // byte offset of x/h slot (768)
#define BATCHES 256
#define NCLASS 10
#define EPSV 1e-5f

#define BSHIFT 9
#define BNODES 512                // nodes per bucket
#define NBUCK ((N_NODES + BNODES - 1) / BNODES)   // 98
#define SEGB (BNODES * R_REL)     // 1536 segments per bucket
#define CAP 9216                  // LDS sort capacity (mean 8192, sigma ~90)
#define NCHUNK 128
#define CHUNK (E_EDGES / NCHUNK)  // 6250 (exact)
#define MATN (NBUCK * NCHUNK)     // 12544

typedef __attribute__((ext_vector_type(8))) short short8v;
typedef __attribute__((ext_vector_type(4))) unsigned uint4v;
typedef __attribute__((ext_vector_type(4))) float float4v;
typedef unsigned short ushort_t;

__device__ __forceinline__ ushort_t f2bf(float f) {
    union { float f; unsigned u; } x; x.f = f;
    unsigned r = x.u + 0x7FFFu + ((x.u >> 16) & 1u);
    return (ushort_t)(r >> 16);
}
__device__ __forceinline__ float bf2f(ushort_t h) {
    union { unsigned u; float f; } x; x.u = ((unsigned)h) << 16;
    return x.f;
}
__device__ __forceinline__ float u2f(unsigned u) {
    union { unsigned u; float f; } x; x.u = u;
    return x.f;
}

// ---------------------------------------------------------------- build x (bf16) into A x-slot
__global__ void build_x_kernel(const int* __restrict__ xi,
                               const float* __restrict__ se,
                               const float* __restrict__ ce,
                               const float* __restrict__ pe,
                               ushort_t* __restrict__ A) {
    int tid = blockIdx.x * blockDim.x + threadIdx.x;   // N*16 threads
    int node = tid >> 4, c = tid & 15;
    if (node >= N_NODES) return;
    int i0 = xi[node * 3 + 0];
    int i1 = xi[node * 3 + 1];
    int i2 = xi[node * 3 + 2];
    i2 = i2 < 0 ? 0 : (i2 > 24 ? 24 : i2);
    const float4* sa = reinterpret_cast<const float4*>(se + (size_t)i0 * DH + c * 8);
    const float4* sb = reinterpret_cast<const float4*>(ce + (size_t)i1 * DH + c * 8);
    const float4* sp = reinterpret_cast<const float4*>(pe + (size_t)i2 * DH + c * 8);
    short8v o;
    #pragma unroll
    for (int q = 0; q < 2; ++q) {
        float4 a = sa[q], b = sb[q], p = sp[q];
        o[q * 4 + 0] = (short)f2bf(a.x + b.x + p.x);
        o[q * 4 + 1] = (short)f2bf(a.y + b.y + p.y);
        o[q * 4 + 2] = (short)f2bf(a.z + b.z + p.z);
        o[q * 4 + 3] = (short)f2bf(a.w + b.w + p.w);
    }
    *reinterpret_cast<short8v*>(A + (size_t)node * KDIM + 3 * DH + c * 8) = o;
}

// ---------------------------------------------------------------- per-(chunk,bucket) histogram
__global__ __launch_bounds__(512) void chunk_hist_kernel(const int* __restrict__ ei,
                                                         int* __restrict__ mat) {
    __shared__ int lh[NBUCK];
    int t = threadIdx.x, blk = blockIdx.x;
    if (t < NBUCK) lh[t] = 0;
    __syncthreads();
    int base = blk * CHUNK;
    for (int i = t; i < CHUNK; i += 512)
        atomicAdd(&lh[ei[E_EDGES + base + i] >> BSHIFT], 1);
    __syncthreads();
    if (t < NBUCK) mat[t * NCHUNK + blk] = lh[t];
}

// ---------------------------------------------------------------- matrix exclusive scan (bucket-major)
__global__ __launch_bounds__(1024) void matscan_kernel(int* __restrict__ mat,
                                                       int* __restrict__ bbase,
                                                       int* __restrict__ offs3) {
    __shared__ int partial[1024];
    int t = threadIdx.x;
    int buf[13];
    int base = t * 13;
    int s = 0;
    #pragma unroll
    for (int j = 0; j < 13; ++j) {
        int idx = base + j;
        int v = (idx < MATN) ? mat[idx] : 0;
        buf[j] = s;                       // exclusive within thread
        s += v;
    }
    partial[t] = s;
    __syncthreads();
    for (int d = 1; d < 1024; d <<= 1) {
        int u = (t >= d) ? partial[t - d] : 0;
        __syncthreads();
        partial[t] += u;
        __syncthreads();
    }
    int off = (t > 0) ? partial[t - 1] : 0;
    #pragma unroll
    for (int j = 0; j < 13; ++j) {
        int idx = base + j;
        if (idx < MATN) mat[idx] = off + buf[j];
    }
    __syncthreads();
    if (t < NBUCK) bbase[t] = mat[t * NCHUNK];
    if (t == 0) { bbase[NBUCK] = E_EDGES; offs3[NSEG] = E_EDGES; }
}

// ---------------------------------------------------------------- chunk counting-sort + coalesced scatter
__global__ __launch_bounds__(512) void chunk_scatter_kernel(const int* __restrict__ ei,
                                                            const int* __restrict__ et,
                                                            const int* __restrict__ mat,
                                                            int* __restrict__ tlist) {
    __shared__ int sorted[CHUNK];          // 25 KB
    __shared__ int lh[NBUCK];              // hist -> cursor
    __shared__ int lstart[NBUCK + 1];
    __shared__ int mbase[NBUCK];
    __shared__ int scr[128];
    int t = threadIdx.x, blk = blockIdx.x;
    if (t < NBUCK) { lh[t] = 0; mbase[t] = mat[t * NCHUNK + blk]; }
    __syncthreads();
    int base = blk * CHUNK;
    for (int i = t; i < CHUNK; i += 512)
        atomicAdd(&lh[ei[E_EDGES + base + i] >> BSHIFT], 1);
    __syncthreads();
    if (t < 128) scr[t] = (t < NBUCK) ? lh[t] : 0;
    __syncthreads();
    for (int d = 1; d < 128; d <<= 1) {
        int u = 0;
        if (t < 128 && t >= d) u = scr[t - d];
        __syncthreads();
        if (t < 128) scr[t] += u;
        __syncthreads();
    }
    if (t < NBUCK) lstart[t] = scr[t] - lh[t];     // exclusive
    if (t == NBUCK - 1) lstart[NBUCK] = scr[t];    // = CHUNK
    __syncthreads();
    if (t < NBUCK) lh[t] = lstart[t];              // cursor
    __syncthreads();
    for (int i = t; i < CHUNK; i += 512) {
        int e = base + i;
        int src = ei[e];
        int dst = ei[E_EDGES + e];
        int r = et[e];
        int b = dst >> BSHIFT;
        int ls = (dst & (BNODES - 1)) * R_REL + r;         // < 1536
        int p = atomicAdd(&lh[b], 1);
        sorted[p] = (ls << 16) | src;                      // src < 2^16
    }
    __syncthreads();
    // linear write: consecutive i within a bucket-run -> consecutive global dest
    for (int i = t; i < CHUNK; i += 512) {
        int lo = 0, hi = NBUCK - 1;                        // largest b with lstart[b] <= i
        while (lo < hi) {
            int mid = (lo + hi + 1) >> 1;
            if (lstart[mid] <= i) lo = mid; else hi = mid - 1;
        }
        tlist[mbase[lo] + (i - lstart[lo])] = sorted[i];
    }
}

// ---------------------------------------------------------------- per-bucket local sort by (node,rel)
__global__ __launch_bounds__(512) void localsort_kernel(const int* __restrict__ tlist,
                                                        const int* __restrict__ bbase,
                                                        int* __restrict__ offs3,
                                                        int* __restrict__ elist) {
    __shared__ int hist[SEGB];             // 6 KB
    __shared__ int scr[512];
    __shared__ int tl[CAP];                // 36 KB
    __shared__ int el[CAP];                // 36 KB
    int b = blockIdx.x, t = threadIdx.x;
    int ebeg = bbase[b], eend = bbase[b + 1];
    int cnt = eend - ebeg;
    int segbase = b * SEGB;
    #pragma unroll
    for (int j = 0; j < 3; ++j) hist[t + j * 512] = 0;
    __syncthreads();

    bool fit = (cnt <= CAP);
    if (fit) {
        for (int i = t; i < cnt; i += 512) {
            int pk = tlist[ebeg + i];
            tl[i] = pk;
            atomicAdd(&hist[pk >> 16], 1);
        }
    } else {
        for (int i = t; i < cnt; i += 512)
            atomicAdd(&hist[tlist[ebeg + i] >> 16], 1);
    }
    __syncthreads();
    // exclusive scan over 1536 entries: thread t owns [3t, 3t+3)
    int h0 = hist[3 * t], h1 = hist[3 * t + 1], h2 = hist[3 * t + 2];
    int s = h0 + h1 + h2;
    scr[t] = s;
    __syncthreads();
    for (int d = 1; d < 512; d <<= 1) {
        int u = (t >= d) ? scr[t - d] : 0;
        __syncthreads();
        scr[t] += u;
        __syncthreads();
    }
    int off = (t > 0) ? scr[t - 1] : 0;
    int e0 = off, e1 = off + h0, e2 = off + h0 + h1;
    {
        int sg = segbase + 3 * t;
        if (sg < NSEG)     offs3[sg]     = ebeg + e0;
        if (sg + 1 < NSEG) offs3[sg + 1] = ebeg + e1;
        if (sg + 2 < NSEG) offs3[sg + 2] = ebeg + e2;
    }
    __syncthreads();
    hist[3 * t] = e0; hist[3 * t + 1] = e1; hist[3 * t + 2] = e2;   // cursors
    __syncthreads();
    if (fit) {
        for (int i = t; i < cnt; i += 512) {
            int pk = tl[i];
            int pos = atomicAdd(&hist[pk >> 16], 1);
            el[pos] = (pk & 0xFFFF) * ROWB + XOFF;
        }
        __syncthreads();
        for (int i = t; i < cnt; i += 512)
            elist[ebeg + i] = el[i];
    } else {
        for (int i = t; i < cnt; i += 512) {
            int pk = tlist[ebeg + i];
            int pos = atomicAdd(&hist[pk >> 16], 1);
            elist[ebeg + pos] = (pk & 0xFFFF) * ROWB + XOFF;
        }
    }
}

// ---------------------------------------------------------------- setup: weight prepack + batch bounds + BN consts
__global__ void setup_kernel(const float* __restrict__ W1, const float* __restrict__ root1,
                             const float* __restrict__ W2, const float* __restrict__ root2,
                             ushort_t* __restrict__ Wf1, ushort_t* __restrict__ Wf2,
                             const int* __restrict__ batch, int* __restrict__ bstart,
                             const float* __restrict__ b1, const float* __restrict__ g1,
                             const float* __restrict__ be1, const float* __restrict__ m1,
                             const float* __restrict__ v1,
                             const float* __restrict__ b2, const float* __restrict__ g2,
                             const float* __restrict__ be2, const float* __restrict__ m2,
                             const float* __restrict__ v2,
                             float* __restrict__ sc1, float* __restrict__ sh1,
                             float* __restrict__ sc2, float* __restrict__ sh2) {
    int tid = blockIdx.x * blockDim.x + threadIdx.x;
    if (tid < 16384) {
        int L = tid >> 13;
        int rem = tid & 8191;
        int l = rem & 63;
        int nt = (rem >> 6) & 7;
        int ks = rem >> 9;
        const float* W = L ? W2 : W1;
        const float* root = L ? root2 : root1;
        ushort_t* dst = (L ? Wf2 : Wf1) + (size_t)rem * 8;
        int col = nt * 16 + (l & 15);
        int kb = ks * 32 + (l >> 4) * 8;
        short8v o;
        #pragma unroll
        for (int j = 0; j < 8; ++j) {
            int k = kb + j;
            float w = (k < 384) ? W[(size_t)k * DH + col] : root[(size_t)(k - 384) * DH + col];
            o[j] = (short)f2bf(w);
        }
        *reinterpret_cast<short8v*>(dst) = o;
    } else if (tid < 16384 + BATCHES + 1) {
        int b = tid - 16384;
        int lo = 0, hi = N_NODES;
        while (lo < hi) {
            int mid = (lo + hi) >> 1;
            if (batch[mid] < b) lo = mid + 1; else hi = mid;
        }
        bstart[b] = lo;
    } else if (tid < 16384 + 257 + DH) {
        int c = tid - 16384 - 257;
        float s = g1[c] * rsqrtf(v1[c] + EPSV);
        sc1[c] = s;
        sh1[c] = (b1[c] - m1[c]) * s + be1[c];
    } else if (tid < 16384 + 257 + 2 * DH) {
        int c = tid - 16384 - 257 - DH;
        float s = g2[c] * rsqrtf(v2[c] + EPSV);
        sc2[c] = s;
        sh2[c] = (b2[c] - m2[c]) * s + be2[c];
    }
}

// ---------------------------------------------------------------- gather aggregation: per-rel means
// 16 lanes per node, 16 nodes per 256-thr block (4 streams/wave), depth-2 pipeline.
__global__ __launch_bounds__(256) void agg_kernel(const char* __restrict__ Ab,
                                                  const int* __restrict__ offs3,
                                                  const int* __restrict__ elist,
                                                  char* __restrict__ Aob) {
    int t = threadIdx.x;
    int g = t >> 4, c = t & 15;
    int n = blockIdx.x * 16 + g;
    if (n >= N_NODES) return;
    int s0 = offs3[3 * n + 0];
    int s1 = offs3[3 * n + 1];
    int s2 = offs3[3 * n + 2];
    int s3 = offs3[3 * n + 3];
    int cb = c * 16;

    float r0l0 = 0, r0h0 = 0, r0l1 = 0, r0h1 = 0, r0l2 = 0, r0h2 = 0, r0l3 = 0, r0h3 = 0;
    float r1l0 = 0, r1h0 = 0, r1l1 = 0, r1h1 = 0, r1l2 = 0, r1h2 = 0, r1l3 = 0, r1h3 = 0;
    float r2l0 = 0, r2h0 = 0, r2l1 = 0, r2h1 = 0, r2l2 = 0, r2h2 = 0, r2l3 = 0, r2h3 = 0;

    #define RUN_SEG(BEG, END, L0, H0, L1, H1, L2, H2, L3, H3)                        \
    {                                                                                \
        int i = (BEG);                                                               \
        uint4v v0, v1;                                                               \
        if (i < (END))                                                               \
            v0 = *reinterpret_cast<const uint4v*>(Ab + elist[i] + cb);               \
        if (i + 1 < (END))                                                           \
            v1 = *reinterpret_cast<const uint4v*>(Ab + elist[i + 1] + cb);           \
        for (; i < (END); ++i) {                                                     \
            uint4v v2;                                                               \
            if (i + 2 < (END))                                                       \
                v2 = *reinterpret_cast<const uint4v*>(Ab + elist[i + 2] + cb);       \
            L0 += u2f(v0[0] << 16); H0 += u2f(v0[0] & 0xFFFF0000u);                  \
            L1 += u2f(v0[1] << 16); H1 += u2f(v0[1] & 0xFFFF0000u);                  \
            L2 += u2f(v0[2] << 16); H2 += u2f(v0[2] & 0xFFFF0000u);                  \
            L3 += u2f(v0[3] << 16); H3 += u2f(v0[3] & 0xFFFF0000u);                  \
            v0 = v1; v1 = v2;                                                        \
        }                                                                            \
    }

    RUN_SEG(s0, s1, r0l0, r0h0, r0l1, r0h1, r0l2, r0h2, r0l3, r0h3)
    RUN_SEG(s1, s2, r1l0, r1h0, r1l1, r1h1, r1l2, r1h2, r1l3, r1h3)
    RUN_SEG(s2, s3, r2l0, r2h0, r2l1, r2h1, r2l2, r2h2, r2l3, r2h3)
    #undef RUN_SEG

    int c0 = s1 - s0, c1 = s2 - s1, c2 = s3 - s2;
    float i0 = c0 ? 1.f / c0 : 0.f;
    float i1 = c1 ? 1.f / c1 : 0.f;
    float i2 = c2 ? 1.f / c2 : 0.f;
    char* base = Aob + (size_t)n * ROWB + cb;
    uint4v o;
    o[0] = (unsigned)f2bf(r0l0 * i0) | ((unsigned)f2bf(r0h0 * i0) << 16);
    o[1] = (unsigned)f2bf(r0l1 * i0) | ((unsigned)f2bf(r0h1 * i0) << 16);
    o[2] = (unsigned)f2bf(r0l2 * i0) | ((unsigned)f2bf(r0h2 * i0) << 16);
    o[3] = (unsigned)f2bf(r0l3 * i0) | ((unsigned)f2bf(r0h3 * i0) << 16);
    *reinterpret_cast<uint4v*>(base + 0 * 256) = o;
    o[0] = (unsigned)f2bf(r1l0 * i1) | ((unsigned)f2bf(r1h0 * i1) << 16);
    o[1] = (unsigned)f2bf(r1l1 * i1) | ((unsigned)f2bf(r1h1 * i1) << 16);
    o[2] = (unsigned)f2bf(r1l2 * i1) | ((unsigned)f2bf(r1h2 * i1) << 16);
    o[3] = (unsigned)f2bf(r1l3 * i1) | ((unsigned)f2bf(r1h3 * i1) << 16);
    *reinterpret_cast<uint4v*>(base + 1 * 256) = o;
    o[0] = (unsigned)f2bf(r2l0 * i2) | ((unsigned)f2bf(r2h0 * i2) << 16);
    o[1] = (unsigned)f2bf(r2l1 * i2) | ((unsigned)f2bf(r2h1 * i2) << 16);
    o[2] = (unsigned)f2bf(r2l2 * i2) | ((unsigned)f2bf(r2h2 * i2) << 16);
    o[3] = (unsigned)f2bf(r2l3 * i2) | ((unsigned)f2bf(r2h3 * i2) << 16);
    *reinterpret_cast<uint4v*>(base + 2 * 256) = o;
}

// ---------------------------------------------------------------- MFMA GEMM + BN + ReLU
__global__ __launch_bounds__(256) void gemm_mfma_kernel(const ushort_t* __restrict__ A,
                                                        const ushort_t* __restrict__ Wf,
                                                        const float* __restrict__ sc,
                                                        const float* __restrict__ sh,
                                                        ushort_t* __restrict__ Aout) {
    int w = threadIdx.x >> 6, l = threadIdx.x & 63;
    int base = blockIdx.x * 64 + w * 16;
    int arow = base + (l & 15);
    if (arow >= N_NODES) arow = N_NODES - 1;           // clamp loads; stores guarded
    const short8v* ap = reinterpret_cast<const short8v*>(A + (size_t)arow * KDIM + (l >> 4) * 8);
    const short8v* wf = reinterpret_cast<const short8v*>(Wf) + l;

    float4v acc[8];
    #pragma unroll
    for (int nt = 0; nt < 8; ++nt) acc[nt] = (float4v){0.f, 0.f, 0.f, 0.f};

    #pragma unroll 4
    for (int ks = 0; ks < 16; ++ks) {
        short8v a = ap[ks * 4];
        const short8v* bp = wf + ks * 512;
        #pragma unroll
        for (int nt = 0; nt < 8; ++nt) {
            short8v b = bp[nt * 64];
            acc[nt] = __builtin_amdgcn_mfma_f32_16x16x32_bf16(a, b, acc[nt], 0, 0, 0);
        }
    }

    int colb = l & 15;
    int rowq = (l >> 4) * 4;
    #pragma unroll
    for (int nt = 0; nt < 8; ++nt) {
        int col = nt * 16 + colb;
        float scv = sc[col], shv = sh[col];
        #pragma unroll
        for (int r = 0; r < 4; ++r) {
            int row = base + rowq + r;
            if (row < N_NODES) {
                float val = fmaxf(acc[nt][r] * scv + shv, 0.f);
                Aout[(size_t)row * KDIM + 3 * DH + col] = f2bf(val);
            }
        }
    }
}

// ---------------------------------------------------------------- fused global-mean-pool + classifier
__global__ __launch_bounds__(256) void pool_cls_kernel(
        const ushort_t* __restrict__ h,             // x/h slot rows, stride KDIM
        const int* __restrict__ bstart,
        const float* __restrict__ clsW,
        const float* __restrict__ clsb,
        float* __restrict__ out) {
    __shared__ float hsh[DH];
    int b = blockIdx.x;
    int t = threadIdx.x;
    int c = t & 127;
    int half = t >> 7;
    int beg = bstart[b], end = bstart[b + 1];
    float s = 0.f;
    for (int n = beg + half; n < end; n += 2)
        s += bf2f(h[(size_t)n * KDIM + c]);
    if (half == 1) hsh[c] = s;
    __syncthreads();
    if (half == 0) {
        float cnt = (float)(end - beg);
        float inv = cnt > 0.f ? 1.f / cnt : 1.f;
        hsh[c] = (s + hsh[c]) * inv;
    }
    __syncthreads();
    if (t < NCLASS) {
        float acc = clsb[t];
        #pragma unroll 16
        for (int d = 0; d < DH; ++d)
            acc += hsh[d] * clsW[d * NCLASS + t];
        out[b * NCLASS + t] = acc;
    }
}

// ---------------------------------------------------------------- launch
extern "C" void kernel_launch(void* const* d_in, const int* in_sizes, int n_in,
                              void* d_out, int out_size, void* d_ws, size_t ws_size,
                              hipStream_t stream) {
    const int*   x_idx  = (const int*)d_in[0];
    const int*   eidx   = (const int*)d_in[1];
    const int*   etype  = (const int*)d_in[2];
    const int*   batch  = (const int*)d_in[3];
    const float* se     = (const float*)d_in[4];
    const float* ce     = (const float*)d_in[5];
    const float* pe     = (const float*)d_in[6];
    const float* W1     = (const float*)d_in[7];
    const float* root1  = (const float*)d_in[8];
    const float* b1     = (const float*)d_in[9];
    const float* g1     = (const float*)d_in[10];
    const float* beta1  = (const float*)d_in[11];
    const float* m1     = (const float*)d_in[12];
    const float* v1     = (const float*)d_in[13];
    const float* W2     = (const float*)d_in[14];
    const float* root2  = (const float*)d_in[15];
    const float* b2     = (const float*)d_in[16];
    const float* g2     = (const float*)d_in[17];
    const float* beta2  = (const float*)d_in[18];
    const float* m2     = (const float*)d_in[19];
    const float* v2     = (const float*)d_in[20];
    const float* clsW   = (const float*)d_in[21];
    const float* clsb   = (const float*)d_in[22];
    float* out = (float*)d_out;

    // workspace layout (16B-aligned blocks)
    char* ws = (char*)d_ws;
    const size_t A_bytes     = (size_t)N_NODES * KDIM * 2;   // 51,200,000
    const size_t elist_bytes = (size_t)E_EDGES * 4;          //  3,200,000
    const size_t tlist_bytes = (size_t)E_EDGES * 4;          //  3,200,000
    const size_t offs3_pad   = 600064;                       // (NSEG+1)*4 padded
    ushort_t* A      = (ushort_t*)(ws);
    int*      elist  = (int*)(ws + A_bytes);
    int*      tlist  = (int*)(ws + A_bytes + elist_bytes);
    int*      offs3  = (int*)(ws + A_bytes + elist_bytes + tlist_bytes);
    char*     p      = ws + A_bytes + elist_bytes + tlist_bytes + offs3_pad;
    int*      mat    = (int*)p;            p += 50176;       // 12544 ints
    int*      bbase  = (int*)p;            p += 512;         // 99 ints padded
    int*      bstart = (int*)p;            p += 1088;
    ushort_t* Wf1    = (ushort_t*)p;       p += 131072;
    ushort_t* Wf2    = (ushort_t*)p;       p += 131072;
    float*    sc1    = (float*)p;          p += 512;
    float*    sh1    = (float*)p;          p += 512;
    float*    sc2    = (float*)p;          p += 512;
    float*    sh2    = (float*)p;          p += 512;

    const int TB = 256;

    // x embeddings (bf16) -> A x-slot
    build_x_kernel<<<(N_NODES * 16 + TB - 1) / TB, TB, 0, stream>>>(x_idx, se, ce, pe, A);

    // fused setup: weight prepack + batch bounds + BN consts
    setup_kernel<<<67, 256, 0, stream>>>(W1, root1, W2, root2, Wf1, Wf2,
                                         batch, bstart,
                                         b1, g1, beta1, m1, v1,
                                         b2, g2, beta2, m2, v2,
                                         sc1, sh1, sc2, sh2);

    // chunked counting-sort CSR build (all scatters via LDS, coalesced global writes)
    chunk_hist_kernel<<<NCHUNK, 512, 0, stream>>>(eidx, mat);
    matscan_kernel<<<1, 1024, 0, stream>>>(mat, bbase, offs3);
    chunk_scatter_kernel<<<NCHUNK, 512, 0, stream>>>(eidx, etype, mat, tlist);
    localsort_kernel<<<NBUCK, 512, 0, stream>>>(tlist, bbase, offs3, elist);

    // ----- layer 1
    agg_kernel<<<(N_NODES + 15) / 16, 256, 0, stream>>>((const char*)A, offs3, elist, (char*)A);
    gemm_mfma_kernel<<<(N_NODES + 63) / 64, 256, 0, stream>>>(A, Wf1, sc1, sh1, A);

    // ----- layer 2
    agg_kernel<<<(N_NODES + 15) / 16, 256, 0, stream>>>((const char*)A, offs3, elist, (char*)A);
    gemm_mfma_kernel<<<(N_NODES + 63) / 64, 256, 0, stream>>>(A, Wf2, sc2, sh2, A);

    // ----- fused global mean pool + classifier
    pool_cls_kernel<<<BATCHES, 256, 0, stream>>>(A + 3 * DH, bstart, clsW, clsb, out);
}

// Round 9
// 222.064 us; speedup vs baseline: 1.6099x; 1.0591x over previous
//
#include <hip/hip_runtime.h>

#define N_NODES 50000
#define E_EDGES 800000
#define R_REL 3
#define NSEG (N_NODES * R_REL)    // 150000 (dst,rel) segments
#define DH 128
#define KDIM 512                  // A row: [mean_r0 | mean_r1 | mean_r2 | x/h] in bf16
#define ROWB 1024                 // bytes per A row
#define XOFF (3 * DH * 2)         // byte offset of x/h slot (768)
#define BATCHES 256
#define NCLASS 10
#define EPSV 1e-5f

#define BSHIFT 9
#define BNODES 512                // nodes per bucket
#define NBUCK ((N_NODES + BNODES - 1) / BNODES)   // 98
#define SEGB (BNODES * R_REL)     // 1536 segments per bucket
#define CAP 9216                  // LDS sort capacity (mean 8192, sigma ~90)
#define NCHUNK 128
#define CHUNK (E_EDGES / NCHUNK)  // 6250 (exact)
#define MATN (NBUCK * NCHUNK)     // 12544

typedef __attribute__((ext_vector_type(8))) short short8v;
typedef __attribute__((ext_vector_type(4))) unsigned uint4v;
typedef __attribute__((ext_vector_type(4))) float float4v;
typedef unsigned short ushort_t;

__device__ __forceinline__ ushort_t f2bf(float f) {
    union { float f; unsigned u; } x; x.f = f;
    unsigned r = x.u + 0x7FFFu + ((x.u >> 16) & 1u);
    return (ushort_t)(r >> 16);
}
__device__ __forceinline__ float bf2f(ushort_t h) {
    union { unsigned u; float f; } x; x.u = ((unsigned)h) << 16;
    return x.f;
}
__device__ __forceinline__ float u2f(unsigned u) {
    union { unsigned u; float f; } x; x.u = u;
    return x.f;
}

// ---------------------------------------------------------------- build x (bf16) into A x-slot
__global__ void build_x_kernel(const int* __restrict__ xi,
                               const float* __restrict__ se,
                               const float* __restrict__ ce,
                               const float* __restrict__ pe,
                               ushort_t* __restrict__ A) {
    int tid = blockIdx.x * blockDim.x + threadIdx.x;   // N*16 threads
    int node = tid >> 4, c = tid & 15;
    if (node >= N_NODES) return;
    int i0 = xi[node * 3 + 0];
    int i1 = xi[node * 3 + 1];
    int i2 = xi[node * 3 + 2];
    i2 = i2 < 0 ? 0 : (i2 > 24 ? 24 : i2);
    const float4* sa = reinterpret_cast<const float4*>(se + (size_t)i0 * DH + c * 8);
    const float4* sb = reinterpret_cast<const float4*>(ce + (size_t)i1 * DH + c * 8);
    const float4* sp = reinterpret_cast<const float4*>(pe + (size_t)i2 * DH + c * 8);
    short8v o;
    #pragma unroll
    for (int q = 0; q < 2; ++q) {
        float4 a = sa[q], b = sb[q], p = sp[q];
        o[q * 4 + 0] = (short)f2bf(a.x + b.x + p.x);
        o[q * 4 + 1] = (short)f2bf(a.y + b.y + p.y);
        o[q * 4 + 2] = (short)f2bf(a.z + b.z + p.z);
        o[q * 4 + 3] = (short)f2bf(a.w + b.w + p.w);
    }
    *reinterpret_cast<short8v*>(A + (size_t)node * KDIM + 3 * DH + c * 8) = o;
}

// ---------------------------------------------------------------- per-(chunk,bucket) histogram
__global__ __launch_bounds__(512) void chunk_hist_kernel(const int* __restrict__ ei,
                                                         int* __restrict__ mat) {
    __shared__ int lh[NBUCK];
    int t = threadIdx.x, blk = blockIdx.x;
    if (t < NBUCK) lh[t] = 0;
    __syncthreads();
    int base = blk * CHUNK;
    for (int i = t; i < CHUNK; i += 512)
        atomicAdd(&lh[ei[E_EDGES + base + i] >> BSHIFT], 1);
    __syncthreads();
    if (t < NBUCK) mat[t * NCHUNK + blk] = lh[t];
}

// ---------------------------------------------------------------- matrix exclusive scan (bucket-major)
__global__ __launch_bounds__(1024) void matscan_kernel(int* __restrict__ mat,
                                                       int* __restrict__ bbase,
                                                       int* __restrict__ offs3) {
    __shared__ int partial[1024];
    int t = threadIdx.x;
    int buf[13];
    int base = t * 13;
    int s = 0;
    #pragma unroll
    for (int j = 0; j < 13; ++j) {
        int idx = base + j;
        int v = (idx < MATN) ? mat[idx] : 0;
        buf[j] = s;                       // exclusive within thread
        s += v;
    }
    partial[t] = s;
    __syncthreads();
    for (int d = 1; d < 1024; d <<= 1) {
        int u = (t >= d) ? partial[t - d] : 0;
        __syncthreads();
        partial[t] += u;
        __syncthreads();
    }
    int off = (t > 0) ? partial[t - 1] : 0;
    #pragma unroll
    for (int j = 0; j < 13; ++j) {
        int idx = base + j;
        if (idx < MATN) mat[idx] = off + buf[j];
    }
    __syncthreads();
    if (t < NBUCK) bbase[t] = mat[t * NCHUNK];
    if (t == 0) { bbase[NBUCK] = E_EDGES; offs3[NSEG] = E_EDGES; }
}

// ---------------------------------------------------------------- chunk counting-sort + coalesced scatter
__global__ __launch_bounds__(512) void chunk_scatter_kernel(const int* __restrict__ ei,
                                                            const int* __restrict__ et,
                                                            const int* __restrict__ mat,
                                                            int* __restrict__ tlist) {
    __shared__ int sorted[CHUNK];          // 25 KB
    __shared__ int lh[NBUCK];              // hist -> cursor
    __shared__ int lstart[NBUCK + 1];
    __shared__ int mbase[NBUCK];
    __shared__ int scr[128];
    int t = threadIdx.x, blk = blockIdx.x;
    if (t < NBUCK) { lh[t] = 0; mbase[t] = mat[t * NCHUNK + blk]; }
    __syncthreads();
    int base = blk * CHUNK;
    for (int i = t; i < CHUNK; i += 512)
        atomicAdd(&lh[ei[E_EDGES + base + i] >> BSHIFT], 1);
    __syncthreads();
    if (t < 128) scr[t] = (t < NBUCK) ? lh[t] : 0;
    __syncthreads();
    for (int d = 1; d < 128; d <<= 1) {
        int u = 0;
        if (t < 128 && t >= d) u = scr[t - d];
        __syncthreads();
        if (t < 128) scr[t] += u;
        __syncthreads();
    }
    if (t < NBUCK) lstart[t] = scr[t] - lh[t];     // exclusive
    if (t == NBUCK - 1) lstart[NBUCK] = scr[t];    // = CHUNK
    __syncthreads();
    if (t < NBUCK) lh[t] = lstart[t];              // cursor
    __syncthreads();
    for (int i = t; i < CHUNK; i += 512) {
        int e = base + i;
        int src = ei[e];
        int dst = ei[E_EDGES + e];
        int r = et[e];
        int b = dst >> BSHIFT;
        int ls = (dst & (BNODES - 1)) * R_REL + r;         // < 1536
        int p = atomicAdd(&lh[b], 1);
        sorted[p] = (ls << 16) | src;                      // src < 2^16
    }
    __syncthreads();
    // linear write: consecutive i within a bucket-run -> consecutive global dest
    for (int i = t; i < CHUNK; i += 512) {
        int lo = 0, hi = NBUCK - 1;                        // largest b with lstart[b] <= i
        while (lo < hi) {
            int mid = (lo + hi + 1) >> 1;
            if (lstart[mid] <= i) lo = mid; else hi = mid - 1;
        }
        tlist[mbase[lo] + (i - lstart[lo])] = sorted[i];
    }
}

// ---------------------------------------------------------------- per-bucket local sort by (node,rel)
__global__ __launch_bounds__(512) void localsort_kernel(const int* __restrict__ tlist,
                                                        const int* __restrict__ bbase,
                                                        int* __restrict__ offs3,
                                                        int* __restrict__ elist) {
    __shared__ int hist[SEGB];             // 6 KB
    __shared__ int scr[512];
    __shared__ int tl[CAP];                // 36 KB
    __shared__ int el[CAP];                // 36 KB
    int b = blockIdx.x, t = threadIdx.x;
    int ebeg = bbase[b], eend = bbase[b + 1];
    int cnt = eend - ebeg;
    int segbase = b * SEGB;
    #pragma unroll
    for (int j = 0; j < 3; ++j) hist[t + j * 512] = 0;
    __syncthreads();

    bool fit = (cnt <= CAP);
    if (fit) {
        for (int i = t; i < cnt; i += 512) {
            int pk = tlist[ebeg + i];
            tl[i] = pk;
            atomicAdd(&hist[pk >> 16], 1);
        }
    } else {
        for (int i = t; i < cnt; i += 512)
            atomicAdd(&hist[tlist[ebeg + i] >> 16], 1);
    }
    __syncthreads();
    // exclusive scan over 1536 entries: thread t owns [3t, 3t+3)
    int h0 = hist[3 * t], h1 = hist[3 * t + 1], h2 = hist[3 * t + 2];
    int s = h0 + h1 + h2;
    scr[t] = s;
    __syncthreads();
    for (int d = 1; d < 512; d <<= 1) {
        int u = (t >= d) ? scr[t - d] : 0;
        __syncthreads();
        scr[t] += u;
        __syncthreads();
    }
    int off = (t > 0) ? scr[t - 1] : 0;
    int e0 = off, e1 = off + h0, e2 = off + h0 + h1;
    {
        int sg = segbase + 3 * t;
        if (sg < NSEG)     offs3[sg]     = ebeg + e0;
        if (sg + 1 < NSEG) offs3[sg + 1] = ebeg + e1;
        if (sg + 2 < NSEG) offs3[sg + 2] = ebeg + e2;
    }
    __syncthreads();
    hist[3 * t] = e0; hist[3 * t + 1] = e1; hist[3 * t + 2] = e2;   // cursors
    __syncthreads();
    if (fit) {
        for (int i = t; i < cnt; i += 512) {
            int pk = tl[i];
            int pos = atomicAdd(&hist[pk >> 16], 1);
            el[pos] = (pk & 0xFFFF) * ROWB + XOFF;
        }
        __syncthreads();
        for (int i = t; i < cnt; i += 512)
            elist[ebeg + i] = el[i];
    } else {
        for (int i = t; i < cnt; i += 512) {
            int pk = tlist[ebeg + i];
            int pos = atomicAdd(&hist[pk >> 16], 1);
            elist[ebeg + pos] = (pk & 0xFFFF) * ROWB + XOFF;
        }
    }
}

// ---------------------------------------------------------------- setup: weight prepack + batch bounds + BN consts
__global__ void setup_kernel(const float* __restrict__ W1, const float* __restrict__ root1,
                             const float* __restrict__ W2, const float* __restrict__ root2,
                             ushort_t* __restrict__ Wf1, ushort_t* __restrict__ Wf2,
                             const int* __restrict__ batch, int* __restrict__ bstart,
                             const float* __restrict__ b1, const float* __restrict__ g1,
                             const float* __restrict__ be1, const float* __restrict__ m1,
                             const float* __restrict__ v1,
                             const float* __restrict__ b2, const float* __restrict__ g2,
                             const float* __restrict__ be2, const float* __restrict__ m2,
                             const float* __restrict__ v2,
                             float* __restrict__ sc1, float* __restrict__ sh1,
                             float* __restrict__ sc2, float* __restrict__ sh2) {
    int tid = blockIdx.x * blockDim.x + threadIdx.x;
    if (tid < 16384) {
        int L = tid >> 13;
        int rem = tid & 8191;
        int l = rem & 63;
        int nt = (rem >> 6) & 7;
        int ks = rem >> 9;
        const float* W = L ? W2 : W1;
        const float* root = L ? root2 : root1;
        ushort_t* dst = (L ? Wf2 : Wf1) + (size_t)rem * 8;
        int col = nt * 16 + (l & 15);
        int kb = ks * 32 + (l >> 4) * 8;
        short8v o;
        #pragma unroll
        for (int j = 0; j < 8; ++j) {
            int k = kb + j;
            float w = (k < 384) ? W[(size_t)k * DH + col] : root[(size_t)(k - 384) * DH + col];
            o[j] = (short)f2bf(w);
        }
        *reinterpret_cast<short8v*>(dst) = o;
    } else if (tid < 16384 + BATCHES + 1) {
        int b = tid - 16384;
        int lo = 0, hi = N_NODES;
        while (lo < hi) {
            int mid = (lo + hi) >> 1;
            if (batch[mid] < b) lo = mid + 1; else hi = mid;
        }
        bstart[b] = lo;
    } else if (tid < 16384 + 257 + DH) {
        int c = tid - 16384 - 257;
        float s = g1[c] * rsqrtf(v1[c] + EPSV);
        sc1[c] = s;
        sh1[c] = (b1[c] - m1[c]) * s + be1[c];
    } else if (tid < 16384 + 257 + 2 * DH) {
        int c = tid - 16384 - 257 - DH;
        float s = g2[c] * rsqrtf(v2[c] + EPSV);
        sc2[c] = s;
        sh2[c] = (b2[c] - m2[c]) * s + be2[c];
    }
}

// ---------------------------------------------------------------- gather aggregation: per-rel means
// 16 lanes per node, 16 nodes per 256-thr block. UNIFIED loop over all 3 segments
// with running-sum snapshots at rel boundaries; batch-4 index+gather pipeline.
__global__ __launch_bounds__(256) void agg_kernel(const char* __restrict__ Ab,
                                                  const int* __restrict__ offs3,
                                                  const int* __restrict__ elist,
                                                  char* __restrict__ Aob) {
    int t = threadIdx.x;
    int g = t >> 4, c = t & 15;
    int n = blockIdx.x * 16 + g;
    if (n >= N_NODES) return;
    int s0 = offs3[3 * n + 0];
    int s1 = offs3[3 * n + 1];
    int s2 = offs3[3 * n + 2];
    int s3 = offs3[3 * n + 3];
    int cb = c * 16;

    float S0 = 0, S1 = 0, S2 = 0, S3 = 0, S4 = 0, S5 = 0, S6 = 0, S7 = 0;   // running sum
    float p0 = 0, p1 = 0, p2 = 0, p3 = 0, p4 = 0, p5 = 0, p6 = 0, p7 = 0;   // snapshot @ s1
    float q0 = 0, q1 = 0, q2 = 0, q3 = 0, q4 = 0, q5 = 0, q6 = 0, q7 = 0;   // snapshot @ s2

    #define ACC8(V)                                           \
        S0 += u2f(V[0] << 16); S1 += u2f(V[0] & 0xFFFF0000u); \
        S2 += u2f(V[1] << 16); S3 += u2f(V[1] & 0xFFFF0000u); \
        S4 += u2f(V[2] << 16); S5 += u2f(V[2] & 0xFFFF0000u); \
        S6 += u2f(V[3] << 16); S7 += u2f(V[3] & 0xFFFF0000u);
    #define SNAPCHK(E)                                                              \
        if ((E) == s1) { p0=S0; p1=S1; p2=S2; p3=S3; p4=S4; p5=S5; p6=S6; p7=S7; }  \
        if ((E) == s2) { q0=S0; q1=S1; q2=S2; q3=S3; q4=S4; q5=S5; q6=S6; q7=S7; }

    int i = s0;
    int bend = s0 + ((s3 - s0) & ~3);
    if (i < bend) {
        int j0 = elist[i], j1 = elist[i + 1], j2 = elist[i + 2], j3 = elist[i + 3];
        uint4v g0 = *reinterpret_cast<const uint4v*>(Ab + j0 + cb);
        uint4v g1 = *reinterpret_cast<const uint4v*>(Ab + j1 + cb);
        uint4v g2 = *reinterpret_cast<const uint4v*>(Ab + j2 + cb);
        uint4v g3 = *reinterpret_cast<const uint4v*>(Ab + j3 + cb);
        for (;;) {
            int inx = i + 4;
            bool more = inx < bend;
            uint4v h0, h1, h2, h3;
            if (more) {
                int k0 = elist[inx], k1 = elist[inx + 1], k2 = elist[inx + 2], k3 = elist[inx + 3];
                h0 = *reinterpret_cast<const uint4v*>(Ab + k0 + cb);
                h1 = *reinterpret_cast<const uint4v*>(Ab + k1 + cb);
                h2 = *reinterpret_cast<const uint4v*>(Ab + k2 + cb);
                h3 = *reinterpret_cast<const uint4v*>(Ab + k3 + cb);
            }
            SNAPCHK(i)     ACC8(g0)
            SNAPCHK(i + 1) ACC8(g1)
            SNAPCHK(i + 2) ACC8(g2)
            SNAPCHK(i + 3) ACC8(g3)
            if (!more) break;
            g0 = h0; g1 = h1; g2 = h2; g3 = h3;
            i = inx;
        }
        i = bend;
    }
    for (; i < s3; ++i) {                      // tail (0-3 edges)
        int j = elist[i];
        uint4v v = *reinterpret_cast<const uint4v*>(Ab + j + cb);
        SNAPCHK(i)
        ACC8(v)
    }
    // boundaries at the very end never fire inside the loop
    if (s1 == s3) { p0=S0; p1=S1; p2=S2; p3=S3; p4=S4; p5=S5; p6=S6; p7=S7; }
    if (s2 == s3) { q0=S0; q1=S1; q2=S2; q3=S3; q4=S4; q5=S5; q6=S6; q7=S7; }
    #undef ACC8
    #undef SNAPCHK

    int c0 = s1 - s0, c1 = s2 - s1, c2 = s3 - s2;
    float i0 = c0 ? 1.f / c0 : 0.f;
    float i1 = c1 ? 1.f / c1 : 0.f;
    float i2 = c2 ? 1.f / c2 : 0.f;
    char* base = Aob + (size_t)n * ROWB + cb;
    uint4v o;
    // mean_r0 = p * i0
    o[0] = (unsigned)f2bf(p0 * i0) | ((unsigned)f2bf(p1 * i0) << 16);
    o[1] = (unsigned)f2bf(p2 * i0) | ((unsigned)f2bf(p3 * i0) << 16);
    o[2] = (unsigned)f2bf(p4 * i0) | ((unsigned)f2bf(p5 * i0) << 16);
    o[3] = (unsigned)f2bf(p6 * i0) | ((unsigned)f2bf(p7 * i0) << 16);
    *reinterpret_cast<uint4v*>(base + 0 * 256) = o;
    // mean_r1 = (q - p) * i1
    o[0] = (unsigned)f2bf((q0 - p0) * i1) | ((unsigned)f2bf((q1 - p1) * i1) << 16);
    o[1] = (unsigned)f2bf((q2 - p2) * i1) | ((unsigned)f2bf((q3 - p3) * i1) << 16);
    o[2] = (unsigned)f2bf((q4 - p4) * i1) | ((unsigned)f2bf((q5 - p5) * i1) << 16);
    o[3] = (unsigned)f2bf((q6 - p6) * i1) | ((unsigned)f2bf((q7 - p7) * i1) << 16);
    *reinterpret_cast<uint4v*>(base + 1 * 256) = o;
    // mean_r2 = (S - q) * i2
    o[0] = (unsigned)f2bf((S0 - q0) * i2) | ((unsigned)f2bf((S1 - q1) * i2) << 16);
    o[1] = (unsigned)f2bf((S2 - q2) * i2) | ((unsigned)f2bf((S3 - q3) * i2) << 16);
    o[2] = (unsigned)f2bf((S4 - q4) * i2) | ((unsigned)f2bf((S5 - q5) * i2) << 16);
    o[3] = (unsigned)f2bf((S6 - q6) * i2) | ((unsigned)f2bf((S7 - q7) * i2) << 16);
    *reinterpret_cast<uint4v*>(base + 2 * 256) = o;
}

// ---------------------------------------------------------------- MFMA GEMM + BN + ReLU
__global__ __launch_bounds__(256) void gemm_mfma_kernel(const ushort_t* __restrict__ A,
                                                        const ushort_t* __restrict__ Wf,
                                                        const float* __restrict__ sc,
                                                        const float* __restrict__ sh,
                                                        ushort_t* __restrict__ Aout) {
    int w = threadIdx.x >> 6, l = threadIdx.x & 63;
    int base = blockIdx.x * 64 + w * 16;
    int arow = base + (l & 15);
    if (arow >= N_NODES) arow = N_NODES - 1;           // clamp loads; stores guarded
    const short8v* ap = reinterpret_cast<const short8v*>(A + (size_t)arow * KDIM + (l >> 4) * 8);
    const short8v* wf = reinterpret_cast<const short8v*>(Wf) + l;

    float4v acc[8];
    #pragma unroll
    for (int nt = 0; nt < 8; ++nt) acc[nt] = (float4v){0.f, 0.f, 0.f, 0.f};

    #pragma unroll 4
    for (int ks = 0; ks < 16; ++ks) {
        short8v a = ap[ks * 4];
        const short8v* bp = wf + ks * 512;
        #pragma unroll
        for (int nt = 0; nt < 8; ++nt) {
            short8v b = bp[nt * 64];
            acc[nt] = __builtin_amdgcn_mfma_f32_16x16x32_bf16(a, b, acc[nt], 0, 0, 0);
        }
    }

    int colb = l & 15;
    int rowq = (l >> 4) * 4;
    #pragma unroll
    for (int nt = 0; nt < 8; ++nt) {
        int col = nt * 16 + colb;
        float scv = sc[col], shv = sh[col];
        #pragma unroll
        for (int r = 0; r < 4; ++r) {
            int row = base + rowq + r;
            if (row < N_NODES) {
                float val = fmaxf(acc[nt][r] * scv + shv, 0.f);
                Aout[(size_t)row * KDIM + 3 * DH + col] = f2bf(val);
            }
        }
    }
}

// ---------------------------------------------------------------- fused global-mean-pool + classifier
__global__ __launch_bounds__(256) void pool_cls_kernel(
        const ushort_t* __restrict__ h,             // x/h slot rows, stride KDIM
        const int* __restrict__ bstart,
        const float* __restrict__ clsW,
        const float* __restrict__ clsb,
        float* __restrict__ out) {
    __shared__ float hsh[DH];
    int b = blockIdx.x;
    int t = threadIdx.x;
    int c = t & 127;
    int half = t >> 7;
    int beg = bstart[b], end = bstart[b + 1];
    float s = 0.f;
    for (int n = beg + half; n < end; n += 2)
        s += bf2f(h[(size_t)n * KDIM + c]);
    if (half == 1) hsh[c] = s;
    __syncthreads();
    if (half == 0) {
        float cnt = (float)(end - beg);
        float inv = cnt > 0.f ? 1.f / cnt : 1.f;
        hsh[c] = (s + hsh[c]) * inv;
    }
    __syncthreads();
    if (t < NCLASS) {
        float acc = clsb[t];
        #pragma unroll 16
        for (int d = 0; d < DH; ++d)
            acc += hsh[d] * clsW[d * NCLASS + t];
        out[b * NCLASS + t] = acc;
    }
}

// ---------------------------------------------------------------- launch
extern "C" void kernel_launch(void* const* d_in, const int* in_sizes, int n_in,
                              void* d_out, int out_size, void* d_ws, size_t ws_size,
                              hipStream_t stream) {
    const int*   x_idx  = (const int*)d_in[0];
    const int*   eidx   = (const int*)d_in[1];
    const int*   etype  = (const int*)d_in[2];
    const int*   batch  = (const int*)d_in[3];
    const float* se     = (const float*)d_in[4];
    const float* ce     = (const float*)d_in[5];
    const float* pe     = (const float*)d_in[6];
    const float* W1     = (const float*)d_in[7];
    const float* root1  = (const float*)d_in[8];
    const float* b1     = (const float*)d_in[9];
    const float* g1     = (const float*)d_in[10];
    const float* beta1  = (const float*)d_in[11];
    const float* m1     = (const float*)d_in[12];
    const float* v1     = (const float*)d_in[13];
    const float* W2     = (const float*)d_in[14];
    const float* root2  = (const float*)d_in[15];
    const float* b2     = (const float*)d_in[16];
    const float* g2     = (const float*)d_in[17];
    const float* beta2  = (const float*)d_in[18];
    const float* m2     = (const float*)d_in[19];
    const float* v2     = (const float*)d_in[20];
    const float* clsW   = (const float*)d_in[21];
    const float* clsb   = (const float*)d_in[22];
    float* out = (float*)d_out;

    // workspace layout (16B-aligned blocks)
    char* ws = (char*)d_ws;
    const size_t A_bytes     = (size_t)N_NODES * KDIM * 2;   // 51,200,000
    const size_t elist_bytes = (size_t)E_EDGES * 4;          //  3,200,000
    const size_t tlist_bytes = (size_t)E_EDGES * 4;          //  3,200,000
    const size_t offs3_pad   = 600064;                       // (NSEG+1)*4 padded
    ushort_t* A      = (ushort_t*)(ws);
    int*      elist  = (int*)(ws + A_bytes);
    int*      tlist  = (int*)(ws + A_bytes + elist_bytes);
    int*      offs3  = (int*)(ws + A_bytes + elist_bytes + tlist_bytes);
    char*     p      = ws + A_bytes + elist_bytes + tlist_bytes + offs3_pad;
    int*      mat    = (int*)p;            p += 50176;       // 12544 ints
    int*      bbase  = (int*)p;            p += 512;         // 99 ints padded
    int*      bstart = (int*)p;            p += 1088;
    ushort_t* Wf1    = (ushort_t*)p;       p += 131072;
    ushort_t* Wf2    = (ushort_t*)p;       p += 131072;
    float*    sc1    = (float*)p;          p += 512;
    float*    sh1    = (float*)p;          p += 512;
    float*    sc2    = (float*)p;          p += 512;
    float*    sh2    = (float*)p;          p += 512;

    const int TB = 256;

    // x embeddings (bf16) -> A x-slot
    build_x_kernel<<<(N_NODES * 16 + TB - 1) / TB, TB, 0, stream>>>(x_idx, se, ce, pe, A);

    // fused setup: weight prepack + batch bounds + BN consts
    setup_kernel<<<67, 256, 0, stream>>>(W1, root1, W2, root2, Wf1, Wf2,
                                         batch, bstart,
                                         b1, g1, beta1, m1, v1,
                                         b2, g2, beta2, m2, v2,
                                         sc1, sh1, sc2, sh2);

    // chunked counting-sort CSR build (all scatters via LDS, coalesced global writes)
    chunk_hist_kernel<<<NCHUNK, 512, 0, stream>>>(eidx, mat);
    matscan_kernel<<<1, 1024, 0, stream>>>(mat, bbase, offs3);
    chunk_scatter_kernel<<<NCHUNK, 512, 0, stream>>>(eidx, etype, mat, tlist);
    localsort_kernel<<<NBUCK, 512, 0, stream>>>(tlist, bbase, offs3, elist);

    // ----- layer 1
    agg_kernel<<<(N_NODES + 15) / 16, 256, 0, stream>>>((const char*)A, offs3, elist, (char*)A);
    gemm_mfma_kernel<<<(N_NODES + 63) / 64, 256, 0, stream>>>(A, Wf1, sc1, sh1, A);

    // ----- layer 2
    agg_kernel<<<(N_NODES + 15) / 16, 256, 0, stream>>>((const char*)A, offs3, elist, (char*)A);
    gemm_mfma_kernel<<<(N_NODES + 63) / 64, 256, 0, stream>>>(A, Wf2, sc2, sh2, A);

    // ----- fused global mean pool + classifier
    pool_cls_kernel<<<BATCHES, 256, 0, stream>>>(A + 3 * DH, bstart, clsW, clsb, out);
}

// Round 10
// 221.366 us; speedup vs baseline: 1.6150x; 1.0032x over previous
//
#include <hip/hip_runtime.h>

#define N_NODES 50000
#define E_EDGES 800000
#define R_REL 3
#define NSEG (N_NODES * R_REL)    // 150000 (dst,rel) segments
#define DH 128
#define KDIM 512                  // A row: [mean_r0 | mean_r1 | mean_r2 | x/h] in bf16
#define ROWB 1024                 // bytes per A row
#define XOFF (3 * DH * 2)         // byte offset of x/h slot (768)
#define BATCHES 256
#define NCLASS 10
#define EPSV 1e-5f

#define BSHIFT 9
#define BNODES 512                // nodes per bucket
#define NBUCK ((N_NODES + BNODES - 1) / BNODES)   // 98
#define SEGB (BNODES * R_REL)     // 1536 segments per bucket
#define CAP 9216                  // LDS sort capacity (mean 8192, sigma ~90)
#define NCHUNK 128
#define CHUNK (E_EDGES / NCHUNK)  // 6250 (exact)
#define MATN (NBUCK * NCHUNK)     // 12544

typedef __attribute__((ext_vector_type(8))) short short8v;
typedef __attribute__((ext_vector_type(4))) unsigned uint4v;
typedef __attribute__((ext_vector_type(4))) float float4v;
typedef unsigned short ushort_t;

__device__ __forceinline__ ushort_t f2bf(float f) {
    union { float f; unsigned u; } x; x.f = f;
    unsigned r = x.u + 0x7FFFu + ((x.u >> 16) & 1u);
    return (ushort_t)(r >> 16);
}
__device__ __forceinline__ float bf2f(ushort_t h) {
    union { unsigned u; float f; } x; x.u = ((unsigned)h) << 16;
    return x.f;
}
__device__ __forceinline__ float u2f(unsigned u) {
    union { unsigned u; float f; } x; x.u = u;
    return x.f;
}

// ---------------------------------------------------------------- build x (bf16) into A x-slot
__global__ void build_x_kernel(const int* __restrict__ xi,
                               const float* __restrict__ se,
                               const float* __restrict__ ce,
                               const float* __restrict__ pe,
                               ushort_t* __restrict__ A) {
    int tid = blockIdx.x * blockDim.x + threadIdx.x;   // N*16 threads
    int node = tid >> 4, c = tid & 15;
    if (node >= N_NODES) return;
    int i0 = xi[node * 3 + 0];
    int i1 = xi[node * 3 + 1];
    int i2 = xi[node * 3 + 2];
    i2 = i2 < 0 ? 0 : (i2 > 24 ? 24 : i2);
    const float4* sa = reinterpret_cast<const float4*>(se + (size_t)i0 * DH + c * 8);
    const float4* sb = reinterpret_cast<const float4*>(ce + (size_t)i1 * DH + c * 8);
    const float4* sp = reinterpret_cast<const float4*>(pe + (size_t)i2 * DH + c * 8);
    short8v o;
    #pragma unroll
    for (int q = 0; q < 2; ++q) {
        float4 a = sa[q], b = sb[q], p = sp[q];
        o[q * 4 + 0] = (short)f2bf(a.x + b.x + p.x);
        o[q * 4 + 1] = (short)f2bf(a.y + b.y + p.y);
        o[q * 4 + 2] = (short)f2bf(a.z + b.z + p.z);
        o[q * 4 + 3] = (short)f2bf(a.w + b.w + p.w);
    }
    *reinterpret_cast<short8v*>(A + (size_t)node * KDIM + 3 * DH + c * 8) = o;
}

// ---------------------------------------------------------------- per-(chunk,bucket) histogram
__global__ __launch_bounds__(512) void chunk_hist_kernel(const int* __restrict__ ei,
                                                         int* __restrict__ mat) {
    __shared__ int lh[NBUCK];
    int t = threadIdx.x, blk = blockIdx.x;
    if (t < NBUCK) lh[t] = 0;
    __syncthreads();
    int base = blk * CHUNK;
    for (int i = t; i < CHUNK; i += 512)
        atomicAdd(&lh[ei[E_EDGES + base + i] >> BSHIFT], 1);
    __syncthreads();
    if (t < NBUCK) mat[t * NCHUNK + blk] = lh[t];
}

// ---------------------------------------------------------------- matrix exclusive scan (bucket-major)
__global__ __launch_bounds__(1024) void matscan_kernel(int* __restrict__ mat,
                                                       int* __restrict__ bbase,
                                                       int* __restrict__ offs3) {
    __shared__ int partial[1024];
    int t = threadIdx.x;
    int buf[13];
    int base = t * 13;
    int s = 0;
    #pragma unroll
    for (int j = 0; j < 13; ++j) {
        int idx = base + j;
        int v = (idx < MATN) ? mat[idx] : 0;
        buf[j] = s;                       // exclusive within thread
        s += v;
    }
    partial[t] = s;
    __syncthreads();
    for (int d = 1; d < 1024; d <<= 1) {
        int u = (t >= d) ? partial[t - d] : 0;
        __syncthreads();
        partial[t] += u;
        __syncthreads();
    }
    int off = (t > 0) ? partial[t - 1] : 0;
    #pragma unroll
    for (int j = 0; j < 13; ++j) {
        int idx = base + j;
        if (idx < MATN) mat[idx] = off + buf[j];
    }
    __syncthreads();
    if (t < NBUCK) bbase[t] = mat[t * NCHUNK];
    if (t == 0) { bbase[NBUCK] = E_EDGES; offs3[NSEG] = E_EDGES; }
}

// ---------------------------------------------------------------- chunk counting-sort + coalesced scatter
__global__ __launch_bounds__(512) void chunk_scatter_kernel(const int* __restrict__ ei,
                                                            const int* __restrict__ et,
                                                            const int* __restrict__ mat,
                                                            int* __restrict__ tlist) {
    __shared__ int sorted[CHUNK];          // 25 KB
    __shared__ int lh[NBUCK];              // hist -> cursor
    __shared__ int lstart[NBUCK + 1];
    __shared__ int mbase[NBUCK];
    __shared__ int scr[128];
    int t = threadIdx.x, blk = blockIdx.x;
    if (t < NBUCK) { lh[t] = 0; mbase[t] = mat[t * NCHUNK + blk]; }
    __syncthreads();
    int base = blk * CHUNK;
    for (int i = t; i < CHUNK; i += 512)
        atomicAdd(&lh[ei[E_EDGES + base + i] >> BSHIFT], 1);
    __syncthreads();
    if (t < 128) scr[t] = (t < NBUCK) ? lh[t] : 0;
    __syncthreads();
    for (int d = 1; d < 128; d <<= 1) {
        int u = 0;
        if (t < 128 && t >= d) u = scr[t - d];
        __syncthreads();
        if (t < 128) scr[t] += u;
        __syncthreads();
    }
    if (t < NBUCK) lstart[t] = scr[t] - lh[t];     // exclusive
    if (t == NBUCK - 1) lstart[NBUCK] = scr[t];    // = CHUNK
    __syncthreads();
    if (t < NBUCK) lh[t] = lstart[t];              // cursor
    __syncthreads();
    for (int i = t; i < CHUNK; i += 512) {
        int e = base + i;
        int src = ei[e];
        int dst = ei[E_EDGES + e];
        int r = et[e];
        int b = dst >> BSHIFT;
        int ls = (dst & (BNODES - 1)) * R_REL + r;         // < 1536
        int p = atomicAdd(&lh[b], 1);
        sorted[p] = (ls << 16) | src;                      // src < 2^16
    }
    __syncthreads();
    // linear write: consecutive i within a bucket-run -> consecutive global dest
    for (int i = t; i < CHUNK; i += 512) {
        int lo = 0, hi = NBUCK - 1;                        // largest b with lstart[b] <= i
        while (lo < hi) {
            int mid = (lo + hi + 1) >> 1;
            if (lstart[mid] <= i) lo = mid; else hi = mid - 1;
        }
        tlist[mbase[lo] + (i - lstart[lo])] = sorted[i];
    }
}

// ---------------------------------------------------------------- per-bucket local sort by (node,rel)
__global__ __launch_bounds__(512) void localsort_kernel(const int* __restrict__ tlist,
                                                        const int* __restrict__ bbase,
                                                        int* __restrict__ offs3,
                                                        int* __restrict__ elist) {
    __shared__ int hist[SEGB];             // 6 KB
    __shared__ int scr[512];
    __shared__ int tl[CAP];                // 36 KB
    __shared__ int el[CAP];                // 36 KB
    int b = blockIdx.x, t = threadIdx.x;
    int ebeg = bbase[b], eend = bbase[b + 1];
    int cnt = eend - ebeg;
    int segbase = b * SEGB;
    #pragma unroll
    for (int j = 0; j < 3; ++j) hist[t + j * 512] = 0;
    __syncthreads();

    bool fit = (cnt <= CAP);
    if (fit) {
        for (int i = t; i < cnt; i += 512) {
            int pk = tlist[ebeg + i];
            tl[i] = pk;
            atomicAdd(&hist[pk >> 16], 1);
        }
    } else {
        for (int i = t; i < cnt; i += 512)
            atomicAdd(&hist[tlist[ebeg + i] >> 16], 1);
    }
    __syncthreads();
    // exclusive scan over 1536 entries: thread t owns [3t, 3t+3)
    int h0 = hist[3 * t], h1 = hist[3 * t + 1], h2 = hist[3 * t + 2];
    int s = h0 + h1 + h2;
    scr[t] = s;
    __syncthreads();
    for (int d = 1; d < 512; d <<= 1) {
        int u = (t >= d) ? scr[t - d] : 0;
        __syncthreads();
        scr[t] += u;
        __syncthreads();
    }
    int off = (t > 0) ? scr[t - 1] : 0;
    int e0 = off, e1 = off + h0, e2 = off + h0 + h1;
    {
        int sg = segbase + 3 * t;
        if (sg < NSEG)     offs3[sg]     = ebeg + e0;
        if (sg + 1 < NSEG) offs3[sg + 1] = ebeg + e1;
        if (sg + 2 < NSEG) offs3[sg + 2] = ebeg + e2;
    }
    __syncthreads();
    hist[3 * t] = e0; hist[3 * t + 1] = e1; hist[3 * t + 2] = e2;   // cursors
    __syncthreads();
    if (fit) {
        for (int i = t; i < cnt; i += 512) {
            int pk = tl[i];
            int pos = atomicAdd(&hist[pk >> 16], 1);
            el[pos] = (pk & 0xFFFF) * ROWB + XOFF;
        }
        __syncthreads();
        for (int i = t; i < cnt; i += 512)
            elist[ebeg + i] = el[i];
    } else {
        for (int i = t; i < cnt; i += 512) {
            int pk = tlist[ebeg + i];
            int pos = atomicAdd(&hist[pk >> 16], 1);
            elist[ebeg + pos] = (pk & 0xFFFF) * ROWB + XOFF;
        }
    }
}

// ---------------------------------------------------------------- setup: weight prepack + batch bounds + BN consts
__global__ void setup_kernel(const float* __restrict__ W1, const float* __restrict__ root1,
                             const float* __restrict__ W2, const float* __restrict__ root2,
                             ushort_t* __restrict__ Wf1, ushort_t* __restrict__ Wf2,
                             const int* __restrict__ batch, int* __restrict__ bstart,
                             const float* __restrict__ b1, const float* __restrict__ g1,
                             const float* __restrict__ be1, const float* __restrict__ m1,
                             const float* __restrict__ v1,
                             const float* __restrict__ b2, const float* __restrict__ g2,
                             const float* __restrict__ be2, const float* __restrict__ m2,
                             const float* __restrict__ v2,
                             float* __restrict__ sc1, float* __restrict__ sh1,
                             float* __restrict__ sc2, float* __restrict__ sh2) {
    int tid = blockIdx.x * blockDim.x + threadIdx.x;
    if (tid < 16384) {
        int L = tid >> 13;
        int rem = tid & 8191;
        int l = rem & 63;
        int nt = (rem >> 6) & 7;
        int ks = rem >> 9;
        const float* W = L ? W2 : W1;
        const float* root = L ? root2 : root1;
        ushort_t* dst = (L ? Wf2 : Wf1) + (size_t)rem * 8;
        int col = nt * 16 + (l & 15);
        int kb = ks * 32 + (l >> 4) * 8;
        short8v o;
        #pragma unroll
        for (int j = 0; j < 8; ++j) {
            int k = kb + j;
            float w = (k < 384) ? W[(size_t)k * DH + col] : root[(size_t)(k - 384) * DH + col];
            o[j] = (short)f2bf(w);
        }
        *reinterpret_cast<short8v*>(dst) = o;
    } else if (tid < 16384 + BATCHES + 1) {
        int b = tid - 16384;
        int lo = 0, hi = N_NODES;
        while (lo < hi) {
            int mid = (lo + hi) >> 1;
            if (batch[mid] < b) lo = mid + 1; else hi = mid;
        }
        bstart[b] = lo;
    } else if (tid < 16384 + 257 + DH) {
        int c = tid - 16384 - 257;
        float s = g1[c] * rsqrtf(v1[c] + EPSV);
        sc1[c] = s;
        sh1[c] = (b1[c] - m1[c]) * s + be1[c];
    } else if (tid < 16384 + 257 + 2 * DH) {
        int c = tid - 16384 - 257 - DH;
        float s = g2[c] * rsqrtf(v2[c] + EPSV);
        sc2[c] = s;
        sh2[c] = (b2[c] - m2[c]) * s + be2[c];
    }
}

// ---------------------------------------------------------------- gather aggregation: per-rel means
// 32 lanes per node as TWO independent 16-lane half-streams over [s0,mid)/[mid,s3);
// unified loop + snapshots; combine 24 partials via __shfl_xor(.,16) (halves are
// lane-partners in the same wave). 8 nodes per 256-thr block; grid 6250 (exact).
__global__ __launch_bounds__(256) void agg_kernel(const char* __restrict__ Ab,
                                                  const int* __restrict__ offs3,
                                                  const int* __restrict__ elist,
                                                  char* __restrict__ Aob) {
    int t = threadIdx.x;
    int c = t & 15;
    int grp = t >> 4;
    int nloc = grp >> 1;
    int half = grp & 1;
    int n = blockIdx.x * 8 + nloc;                 // N_NODES = 8*6250 exactly
    int s0 = offs3[3 * n + 0];
    int s1 = offs3[3 * n + 1];
    int s2 = offs3[3 * n + 2];
    int s3 = offs3[3 * n + 3];
    int mid = (s0 + s3) >> 1;
    int rb = half ? mid : s0;
    int re = half ? s3 : mid;
    int cb = c * 16;

    float S0 = 0, S1 = 0, S2 = 0, S3 = 0, S4 = 0, S5 = 0, S6 = 0, S7 = 0;   // running sum
    float p0 = 0, p1 = 0, p2 = 0, p3 = 0, p4 = 0, p5 = 0, p6 = 0, p7 = 0;   // snapshot @ s1
    float q0 = 0, q1 = 0, q2 = 0, q3 = 0, q4 = 0, q5 = 0, q6 = 0, q7 = 0;   // snapshot @ s2

    #define ACC8(V)                                           \
        S0 += u2f(V[0] << 16); S1 += u2f(V[0] & 0xFFFF0000u); \
        S2 += u2f(V[1] << 16); S3 += u2f(V[1] & 0xFFFF0000u); \
        S4 += u2f(V[2] << 16); S5 += u2f(V[2] & 0xFFFF0000u); \
        S6 += u2f(V[3] << 16); S7 += u2f(V[3] & 0xFFFF0000u);
    #define SNAPCHK(E)                                                              \
        if ((E) == s1) { p0=S0; p1=S1; p2=S2; p3=S3; p4=S4; p5=S5; p6=S6; p7=S7; }  \
        if ((E) == s2) { q0=S0; q1=S1; q2=S2; q3=S3; q4=S4; q5=S5; q6=S6; q7=S7; }

    int i = rb;
    int bend = rb + ((re - rb) & ~3);
    if (i < bend) {
        int j0 = elist[i], j1 = elist[i + 1], j2 = elist[i + 2], j3 = elist[i + 3];
        uint4v g0 = *reinterpret_cast<const uint4v*>(Ab + j0 + cb);
        uint4v g1 = *reinterpret_cast<const uint4v*>(Ab + j1 + cb);
        uint4v g2 = *reinterpret_cast<const uint4v*>(Ab + j2 + cb);
        uint4v g3 = *reinterpret_cast<const uint4v*>(Ab + j3 + cb);
        for (;;) {
            int inx = i + 4;
            bool more = inx < bend;
            uint4v h0, h1, h2, h3;
            if (more) {
                int k0 = elist[inx], k1 = elist[inx + 1], k2 = elist[inx + 2], k3 = elist[inx + 3];
                h0 = *reinterpret_cast<const uint4v*>(Ab + k0 + cb);
                h1 = *reinterpret_cast<const uint4v*>(Ab + k1 + cb);
                h2 = *reinterpret_cast<const uint4v*>(Ab + k2 + cb);
                h3 = *reinterpret_cast<const uint4v*>(Ab + k3 + cb);
            }
            SNAPCHK(i)     ACC8(g0)
            SNAPCHK(i + 1) ACC8(g1)
            SNAPCHK(i + 2) ACC8(g2)
            SNAPCHK(i + 3) ACC8(g3)
            if (!more) break;
            g0 = h0; g1 = h1; g2 = h2; g3 = h3;
            i = inx;
        }
        i = bend;
    }
    for (; i < re; ++i) {                      // tail (0-3 edges)
        int j = elist[i];
        uint4v v = *reinterpret_cast<const uint4v*>(Ab + j + cb);
        SNAPCHK(i)
        ACC8(v)
    }
    // boundaries at/after this half's end
    if (s1 >= re) { p0=S0; p1=S1; p2=S2; p3=S3; p4=S4; p5=S5; p6=S6; p7=S7; }
    if (s2 >= re) { q0=S0; q1=S1; q2=S2; q3=S3; q4=S4; q5=S5; q6=S6; q7=S7; }
    #undef ACC8
    #undef SNAPCHK

    // combine the two half-streams (lane partners l ^ 16 within the wave)
    S0 += __shfl_xor(S0, 16); S1 += __shfl_xor(S1, 16);
    S2 += __shfl_xor(S2, 16); S3 += __shfl_xor(S3, 16);
    S4 += __shfl_xor(S4, 16); S5 += __shfl_xor(S5, 16);
    S6 += __shfl_xor(S6, 16); S7 += __shfl_xor(S7, 16);
    p0 += __shfl_xor(p0, 16); p1 += __shfl_xor(p1, 16);
    p2 += __shfl_xor(p2, 16); p3 += __shfl_xor(p3, 16);
    p4 += __shfl_xor(p4, 16); p5 += __shfl_xor(p5, 16);
    p6 += __shfl_xor(p6, 16); p7 += __shfl_xor(p7, 16);
    q0 += __shfl_xor(q0, 16); q1 += __shfl_xor(q1, 16);
    q2 += __shfl_xor(q2, 16); q3 += __shfl_xor(q3, 16);
    q4 += __shfl_xor(q4, 16); q5 += __shfl_xor(q5, 16);
    q6 += __shfl_xor(q6, 16); q7 += __shfl_xor(q7, 16);

    if (half) return;

    int c0 = s1 - s0, c1 = s2 - s1, c2 = s3 - s2;
    float i0 = c0 ? 1.f / c0 : 0.f;
    float i1 = c1 ? 1.f / c1 : 0.f;
    float i2 = c2 ? 1.f / c2 : 0.f;
    char* base = Aob + (size_t)n * ROWB + cb;
    uint4v o;
    // mean_r0 = p * i0
    o[0] = (unsigned)f2bf(p0 * i0) | ((unsigned)f2bf(p1 * i0) << 16);
    o[1] = (unsigned)f2bf(p2 * i0) | ((unsigned)f2bf(p3 * i0) << 16);
    o[2] = (unsigned)f2bf(p4 * i0) | ((unsigned)f2bf(p5 * i0) << 16);
    o[3] = (unsigned)f2bf(p6 * i0) | ((unsigned)f2bf(p7 * i0) << 16);
    *reinterpret_cast<uint4v*>(base + 0 * 256) = o;
    // mean_r1 = (q - p) * i1
    o[0] = (unsigned)f2bf((q0 - p0) * i1) | ((unsigned)f2bf((q1 - p1) * i1) << 16);
    o[1] = (unsigned)f2bf((q2 - p2) * i1) | ((unsigned)f2bf((q3 - p3) * i1) << 16);
    o[2] = (unsigned)f2bf((q4 - p4) * i1) | ((unsigned)f2bf((q5 - p5) * i1) << 16);
    o[3] = (unsigned)f2bf((q6 - p6) * i1) | ((unsigned)f2bf((q7 - p7) * i1) << 16);
    *reinterpret_cast<uint4v*>(base + 1 * 256) = o;
    // mean_r2 = (S - q) * i2
    o[0] = (unsigned)f2bf((S0 - q0) * i2) | ((unsigned)f2bf((S1 - q1) * i2) << 16);
    o[1] = (unsigned)f2bf((S2 - q2) * i2) | ((unsigned)f2bf((S3 - q3) * i2) << 16);
    o[2] = (unsigned)f2bf((S4 - q4) * i2) | ((unsigned)f2bf((S5 - q5) * i2) << 16);
    o[3] = (unsigned)f2bf((S6 - q6) * i2) | ((unsigned)f2bf((S7 - q7) * i2) << 16);
    *reinterpret_cast<uint4v*>(base + 2 * 256) = o;
}

// ---------------------------------------------------------------- MFMA GEMM + BN + ReLU
// out row stride / col offset parameterized: layer1 -> A x-slot, layer2 -> compact h2
__global__ __launch_bounds__(256) void gemm_mfma_kernel(const ushort_t* __restrict__ A,
                                                        const ushort_t* __restrict__ Wf,
                                                        const float* __restrict__ sc,
                                                        const float* __restrict__ sh,
                                                        ushort_t* __restrict__ Aout,
                                                        int ostride, int ooff) {
    int w = threadIdx.x >> 6, l = threadIdx.x & 63;
    int base = blockIdx.x * 64 + w * 16;
    int arow = base + (l & 15);
    if (arow >= N_NODES) arow = N_NODES - 1;           // clamp loads; stores guarded
    const short8v* ap = reinterpret_cast<const short8v*>(A + (size_t)arow * KDIM + (l >> 4) * 8);
    const short8v* wf = reinterpret_cast<const short8v*>(Wf) + l;

    float4v acc[8];
    #pragma unroll
    for (int nt = 0; nt < 8; ++nt) acc[nt] = (float4v){0.f, 0.f, 0.f, 0.f};

    #pragma unroll 4
    for (int ks = 0; ks < 16; ++ks) {
        short8v a = ap[ks * 4];
        const short8v* bp = wf + ks * 512;
        #pragma unroll
        for (int nt = 0; nt < 8; ++nt) {
            short8v b = bp[nt * 64];
            acc[nt] = __builtin_amdgcn_mfma_f32_16x16x32_bf16(a, b, acc[nt], 0, 0, 0);
        }
    }

    int colb = l & 15;
    int rowq = (l >> 4) * 4;
    #pragma unroll
    for (int nt = 0; nt < 8; ++nt) {
        int col = nt * 16 + colb;
        float scv = sc[col], shv = sh[col];
        #pragma unroll
        for (int r = 0; r < 4; ++r) {
            int row = base + rowq + r;
            if (row < N_NODES) {
                float val = fmaxf(acc[nt][r] * scv + shv, 0.f);
                Aout[(size_t)row * ostride + ooff + col] = f2bf(val);
            }
        }
    }
}

// ---------------------------------------------------------------- fused global-mean-pool + classifier
__global__ __launch_bounds__(256) void pool_cls_kernel(
        const ushort_t* __restrict__ h,             // compact [N][DH] bf16
        const int* __restrict__ bstart,
        const float* __restrict__ clsW,
        const float* __restrict__ clsb,
        float* __restrict__ out) {
    __shared__ float hsh[DH];
    int b = blockIdx.x;
    int t = threadIdx.x;
    int c = t & 127;
    int half = t >> 7;
    int beg = bstart[b], end = bstart[b + 1];
    float s = 0.f;
    for (int n = beg + half; n < end; n += 2)
        s += bf2f(h[(size_t)n * DH + c]);
    if (half == 1) hsh[c] = s;
    __syncthreads();
    if (half == 0) {
        float cnt = (float)(end - beg);
        float inv = cnt > 0.f ? 1.f / cnt : 1.f;
        hsh[c] = (s + hsh[c]) * inv;
    }
    __syncthreads();
    if (t < NCLASS) {
        float acc = clsb[t];
        #pragma unroll 16
        for (int d = 0; d < DH; ++d)
            acc += hsh[d] * clsW[d * NCLASS + t];
        out[b * NCLASS + t] = acc;
    }
}

// ---------------------------------------------------------------- launch
extern "C" void kernel_launch(void* const* d_in, const int* in_sizes, int n_in,
                              void* d_out, int out_size, void* d_ws, size_t ws_size,
                              hipStream_t stream) {
    const int*   x_idx  = (const int*)d_in[0];
    const int*   eidx   = (const int*)d_in[1];
    const int*   etype  = (const int*)d_in[2];
    const int*   batch  = (const int*)d_in[3];
    const float* se     = (const float*)d_in[4];
    const float* ce     = (const float*)d_in[5];
    const float* pe     = (const float*)d_in[6];
    const float* W1     = (const float*)d_in[7];
    const float* root1  = (const float*)d_in[8];
    const float* b1     = (const float*)d_in[9];
    const float* g1     = (const float*)d_in[10];
    const float* beta1  = (const float*)d_in[11];
    const float* m1     = (const float*)d_in[12];
    const float* v1     = (const float*)d_in[13];
    const float* W2     = (const float*)d_in[14];
    const float* root2  = (const float*)d_in[15];
    const float* b2     = (const float*)d_in[16];
    const float* g2     = (const float*)d_in[17];
    const float* beta2  = (const float*)d_in[18];
    const float* m2     = (const float*)d_in[19];
    const float* v2     = (const float*)d_in[20];
    const float* clsW   = (const float*)d_in[21];
    const float* clsb   = (const float*)d_in[22];
    float* out = (float*)d_out;

    // workspace layout (16B-aligned blocks)
    char* ws = (char*)d_ws;
    const size_t A_bytes     = (size_t)N_NODES * KDIM * 2;   // 51,200,000
    const size_t elist_bytes = (size_t)E_EDGES * 4;          //  3,200,000
    const size_t tlist_bytes = (size_t)E_EDGES * 4;          //  3,200,000
    const size_t offs3_pad   = 600064;                       // (NSEG+1)*4 padded
    ushort_t* A      = (ushort_t*)(ws);
    int*      elist  = (int*)(ws + A_bytes);
    int*      tlist  = (int*)(ws + A_bytes + elist_bytes);
    int*      offs3  = (int*)(ws + A_bytes + elist_bytes + tlist_bytes);
    char*     p      = ws + A_bytes + elist_bytes + tlist_bytes + offs3_pad;
    int*      mat    = (int*)p;            p += 50176;       // 12544 ints
    int*      bbase  = (int*)p;            p += 512;         // 99 ints padded
    int*      bstart = (int*)p;            p += 1088;
    ushort_t* Wf1    = (ushort_t*)p;       p += 131072;
    ushort_t* Wf2    = (ushort_t*)p;       p += 131072;
    float*    sc1    = (float*)p;          p += 512;
    float*    sh1    = (float*)p;          p += 512;
    float*    sc2    = (float*)p;          p += 512;
    float*    sh2    = (float*)p;          p += 512;
    ushort_t* H2     = (ushort_t*)p;       p += (size_t)N_NODES * DH * 2;   // 12.8 MB

    const int TB = 256;

    // x embeddings (bf16) -> A x-slot
    build_x_kernel<<<(N_NODES * 16 + TB - 1) / TB, TB, 0, stream>>>(x_idx, se, ce, pe, A);

    // fused setup: weight prepack + batch bounds + BN consts
    setup_kernel<<<67, 256, 0, stream>>>(W1, root1, W2, root2, Wf1, Wf2,
                                         batch, bstart,
                                         b1, g1, beta1, m1, v1,
                                         b2, g2, beta2, m2, v2,
                                         sc1, sh1, sc2, sh2);

    // chunked counting-sort CSR build (all scatters via LDS, coalesced global writes)
    chunk_hist_kernel<<<NCHUNK, 512, 0, stream>>>(eidx, mat);
    matscan_kernel<<<1, 1024, 0, stream>>>(mat, bbase, offs3);
    chunk_scatter_kernel<<<NCHUNK, 512, 0, stream>>>(eidx, etype, mat, tlist);
    localsort_kernel<<<NBUCK, 512, 0, stream>>>(tlist, bbase, offs3, elist);

    // ----- layer 1
    agg_kernel<<<N_NODES / 8, 256, 0, stream>>>((const char*)A, offs3, elist, (char*)A);
    gemm_mfma_kernel<<<(N_NODES + 63) / 64, 256, 0, stream>>>(A, Wf1, sc1, sh1,
                                                              A, KDIM, 3 * DH);

    // ----- layer 2
    agg_kernel<<<N_NODES / 8, 256, 0, stream>>>((const char*)A, offs3, elist, (char*)A);
    gemm_mfma_kernel<<<(N_NODES + 63) / 64, 256, 0, stream>>>(A, Wf2, sc2, sh2,
                                                              H2, DH, 0);

    // ----- fused global mean pool + classifier (compact h2)
    pool_cls_kernel<<<BATCHES, 256, 0, stream>>>(H2, bstart, clsW, clsb, out);
}